// Round 1
// baseline (1531.002 us; speedup 1.0000x reference)
//
#include <hip/hip_runtime.h>

#define N_NODES 50000
#define M_EDGES 800000
#define D_EMB   256
#define H_HEADS 8

// ---- monotonic float<->unsigned encoding for atomicMax on floats ----
static __device__ __forceinline__ unsigned enc_ord(float f) {
    unsigned b = __float_as_uint(f);
    return (b & 0x80000000u) ? ~b : (b | 0x80000000u);
}
static __device__ __forceinline__ float dec_ord(unsigned u) {
    unsigned b = (u & 0x80000000u) ? (u ^ 0x80000000u) : ~u;
    return __uint_as_float(b);
}

// ---- init: zero CSR counters + gmax (ws is poisoned 0xAA before every call) ----
__global__ void init_kernel(int* counts, int* cursor, unsigned* gmax) {
    int t = blockIdx.x * blockDim.x + threadIdx.x;
    if (t < N_NODES) { counts[t] = 0; cursor[t] = 0; }
    if (t == 0) *gmax = 0u;
}

// ---- fp32 GEMM: C[n][j] = (relu?)(sum_k A[n][k]*W[k][j] + bias[j]) (+ residual)
// tile 64x64, BK=16, 256 threads (16x16), 4x4 micro-tile
__global__ __launch_bounds__(256) void gemm_kernel(
    const float* __restrict__ A, const float* __restrict__ W,
    const float* __restrict__ bias, const float* __restrict__ residual,
    float* __restrict__ C, int nrows, int do_relu) {
    __shared__ float As[64][17];
    __shared__ float Ws[16][64];
    int row0 = blockIdx.x * 64;
    int col0 = blockIdx.y * 64;
    int tid = threadIdx.x;
    int tx = tid & 15, ty = tid >> 4;
    float acc[4][4] = {};
    for (int kk = 0; kk < 256; kk += 16) {
        {
            int r = tid >> 2, kq = (tid & 3) * 4;
            int grow = row0 + r;
            float4 v = make_float4(0.f, 0.f, 0.f, 0.f);
            if (grow < nrows) v = *(const float4*)(A + (size_t)grow * 256 + kk + kq);
            As[r][kq + 0] = v.x; As[r][kq + 1] = v.y;
            As[r][kq + 2] = v.z; As[r][kq + 3] = v.w;
        }
        {
            int k = tid >> 4, cq = (tid & 15) * 4;
            float4 v = *(const float4*)(W + (size_t)(kk + k) * 256 + col0 + cq);
            Ws[k][cq + 0] = v.x; Ws[k][cq + 1] = v.y;
            Ws[k][cq + 2] = v.z; Ws[k][cq + 3] = v.w;
        }
        __syncthreads();
        #pragma unroll
        for (int k = 0; k < 16; k++) {
            float a[4], b[4];
            #pragma unroll
            for (int i = 0; i < 4; i++) a[i] = As[ty * 4 + i][k];
            #pragma unroll
            for (int j = 0; j < 4; j++) b[j] = Ws[k][tx * 4 + j];
            #pragma unroll
            for (int i = 0; i < 4; i++)
                #pragma unroll
                for (int j = 0; j < 4; j++) acc[i][j] += a[i] * b[j];
        }
        __syncthreads();
    }
    #pragma unroll
    for (int i = 0; i < 4; i++) {
        int grow = row0 + ty * 4 + i;
        if (grow >= nrows) break;
        #pragma unroll
        for (int j = 0; j < 4; j++) {
            int gcol = col0 + tx * 4 + j;
            float v = acc[i][j] + bias[gcol];
            if (do_relu) v = fmaxf(v, 0.f);
            if (residual) v += residual[(size_t)grow * 256 + gcol];
            C[(size_t)grow * 256 + gcol] = v;
        }
    }
}

// ---- CSR build: histogram by receiver ----
__global__ void hist_kernel(const int* __restrict__ recv, int* __restrict__ counts) {
    int t = blockIdx.x * 256 + threadIdx.x;
    if (t < M_EDGES) atomicAdd(&counts[recv[t]], 1);
}

// ---- exclusive scan over counts (single block, 256 threads) ----
__global__ void scan_kernel(const int* __restrict__ counts, int* __restrict__ offsets) {
    __shared__ int part[256];
    int t = threadIdx.x;
    const int per = (N_NODES + 255) / 256;  // 196
    int start = t * per;
    int end = min(start + per, N_NODES);
    int s = 0;
    for (int i = start; i < end; i++) s += counts[i];
    part[t] = s;
    __syncthreads();
    if (t == 0) {
        int acc = 0;
        for (int i = 0; i < 256; i++) { int v = part[i]; part[i] = acc; acc += v; }
    }
    __syncthreads();
    int acc = part[t];
    for (int i = start; i < end; i++) { offsets[i] = acc; acc += counts[i]; }
    if (end == N_NODES && start < N_NODES) offsets[N_NODES] = acc;
}

// ---- CSR fill: scatter edge ids into receiver-sorted order ----
__global__ void fill_kernel(const int* __restrict__ recv, const int* __restrict__ offsets,
                            int* __restrict__ cursor, int* __restrict__ esorted) {
    int t = blockIdx.x * 256 + threadIdx.x;
    if (t < M_EDGES) {
        int r = recv[t];
        int pos = offsets[r] + atomicAdd(&cursor[r], 1);
        esorted[pos] = t;
    }
}

// ---- edge logits: qk[e][h] = Q[recv[e],h,:] . K[send[e],h,:]; global max ----
__global__ __launch_bounds__(256) void qk_kernel(
    const int* __restrict__ recv, const int* __restrict__ send,
    const float* __restrict__ Q, const float* __restrict__ K,
    float* __restrict__ qk, unsigned* __restrict__ gmax) {
    __shared__ unsigned smax;
    if (threadIdx.x == 0) smax = 0u;
    __syncthreads();
    int t = blockIdx.x * 256 + threadIdx.x;
    int e = t >> 3, h = t & 7;
    if (e < M_EDGES) {
        const float4* q = (const float4*)(Q + (size_t)recv[e] * 256 + h * 32);
        const float4* k = (const float4*)(K + (size_t)send[e] * 256 + h * 32);
        float dot = 0.f;
        #pragma unroll
        for (int i = 0; i < 8; i++) {
            float4 a = q[i], b = k[i];
            dot += a.x * b.x + a.y * b.y + a.z * b.z + a.w * b.w;
        }
        qk[(size_t)e * 8 + h] = dot;
        atomicMax(&smax, enc_ord(dot));
    }
    __syncthreads();
    if (threadIdx.x == 0) atomicMax(gmax, smax);
}

// ---- per-node segment softmax + weighted gather of V; msg = relu(agg) ----
__global__ __launch_bounds__(256) void node_agg_kernel(
    const int* __restrict__ send, const int* __restrict__ offsets,
    const int* __restrict__ esorted, const float* __restrict__ qk,
    const float* __restrict__ V, const unsigned* __restrict__ gmax,
    float* __restrict__ msg) {
    int n = blockIdx.x;
    int c = threadIdx.x;       // c = h*32 + v
    int h = c >> 5;
    int off = offsets[n];
    int deg = offsets[n + 1] - off;
    float scale = 3.0f / dec_ord(*gmax);
    float sum = 0.f;
    for (int i = 0; i < deg; i++) {
        int e = esorted[off + i];
        sum += __expf(qk[(size_t)e * 8 + h] * scale);
    }
    float inv = (deg > 0) ? 1.0f / (sum * 5.65685424949238f) : 0.f;  // sqrt(32)
    float acc = 0.f;
    for (int i = 0; i < deg; i++) {
        int e = esorted[off + i];
        float a = __expf(qk[(size_t)e * 8 + h] * scale);
        acc += a * V[(size_t)send[e] * 256 + c];
    }
    msg[(size_t)n * 256 + c] = fmaxf(acc * inv, 0.f);
}

extern "C" void kernel_launch(void* const* d_in, const int* in_sizes, int n_in,
                              void* d_out, int out_size, void* d_ws, size_t ws_size,
                              hipStream_t stream) {
    const float* x    = (const float*)d_in[0];
    const int*   edge = (const int*)d_in[1];
    const int*   recv = edge;
    const int*   send = edge + M_EDGES;
    const float* Wk   = (const float*)d_in[2];
    const float* bk   = (const float*)d_in[3];
    const float* Wq   = (const float*)d_in[4];
    const float* bq   = (const float*)d_in[5];
    const float* Wv   = (const float*)d_in[6];
    const float* bv   = (const float*)d_in[7];
    const float* Wagg = (const float*)d_in[8];
    const float* bagg = (const float*)d_in[9];
    const float* Wff  = (const float*)d_in[10];
    const float* bff  = (const float*)d_in[11];
    float* out = (float*)d_out;

    // workspace layout (~183 MB)
    float* Kbuf   = (float*)d_ws;
    float* Qbuf   = Kbuf + (size_t)N_NODES * 256;
    float* Vbuf   = Qbuf + (size_t)N_NODES * 256;
    float* qkbuf  = Vbuf + (size_t)N_NODES * 256;
    int* counts   = (int*)(qkbuf + (size_t)M_EDGES * 8);
    int* cursor   = counts + N_NODES;
    int* offsets  = cursor + N_NODES;
    int* esorted  = offsets + N_NODES + 1;
    unsigned* gmax = (unsigned*)(esorted + M_EDGES);
    float* msg    = Kbuf;  // reuse: K dead after qk_kernel
    float* hidden = Qbuf;  // reuse: Q dead after qk_kernel

    dim3 blk(256);
    dim3 gemm_grid((N_NODES + 63) / 64, 4);
    dim3 edge_grid((M_EDGES + 255) / 256);

    hipLaunchKernelGGL(init_kernel, dim3((N_NODES + 255) / 256), blk, 0, stream,
                       counts, cursor, gmax);
    // projections
    hipLaunchKernelGGL(gemm_kernel, gemm_grid, blk, 0, stream, x, Wk, bk, nullptr, Kbuf, N_NODES, 0);
    hipLaunchKernelGGL(gemm_kernel, gemm_grid, blk, 0, stream, x, Wq, bq, nullptr, Qbuf, N_NODES, 0);
    hipLaunchKernelGGL(gemm_kernel, gemm_grid, blk, 0, stream, x, Wv, bv, nullptr, Vbuf, N_NODES, 0);
    // CSR build
    hipLaunchKernelGGL(hist_kernel, edge_grid, blk, 0, stream, recv, counts);
    hipLaunchKernelGGL(scan_kernel, dim3(1), blk, 0, stream, counts, offsets);
    hipLaunchKernelGGL(fill_kernel, edge_grid, blk, 0, stream, recv, offsets, cursor, esorted);
    // edge logits + global max
    hipLaunchKernelGGL(qk_kernel, dim3((M_EDGES * 8 + 255) / 256), blk, 0, stream,
                       recv, send, Qbuf, Kbuf, qkbuf, gmax);
    // segment softmax + aggregate
    hipLaunchKernelGGL(node_agg_kernel, dim3(N_NODES), blk, 0, stream,
                       send, offsets, esorted, qkbuf, Vbuf, gmax, msg);
    // output MLP
    hipLaunchKernelGGL(gemm_kernel, gemm_grid, blk, 0, stream, msg, Wagg, bagg, nullptr, hidden, N_NODES, 1);
    hipLaunchKernelGGL(gemm_kernel, gemm_grid, blk, 0, stream, hidden, Wff, bff, x, out, N_NODES, 1);
}

// Round 2
// 1139.393 us; speedup vs baseline: 1.3437x; 1.3437x over previous
//
#include <hip/hip_runtime.h>

#define N_NODES 50000
#define M_EDGES 800000

typedef __bf16 bf16x8 __attribute__((ext_vector_type(8)));
typedef __bf16 bf16x4 __attribute__((ext_vector_type(4)));
typedef float  f32x4  __attribute__((ext_vector_type(4)));

// ---- monotonic float<->unsigned encoding for atomicMax on floats ----
static __device__ __forceinline__ unsigned enc_ord(float f) {
    unsigned b = __float_as_uint(f);
    return (b & 0x80000000u) ? ~b : (b | 0x80000000u);
}
static __device__ __forceinline__ float dec_ord(unsigned u) {
    unsigned b = (u & 0x80000000u) ? (u ^ 0x80000000u) : ~u;
    return __uint_as_float(b);
}

// ---- init: zero CSR counters + gmax ----
__global__ void init_kernel(int* counts, int* cursor, unsigned* gmax) {
    int t = blockIdx.x * blockDim.x + threadIdx.x;
    if (t < N_NODES) { counts[t] = 0; cursor[t] = 0; }
    if (t == 0) *gmax = 0u;
}

// ---- weight transpose + hi/lo bf16 split: th[n*256+k] = bf16(W[k*256+n]) ----
__global__ void wsplit_kernel(const float* __restrict__ W,
                              __bf16* __restrict__ th, __bf16* __restrict__ tl) {
    int t = blockIdx.x * 256 + threadIdx.x;   // 65536 threads
    int n = t >> 8, k = t & 255;
    float v = W[(size_t)k * 256 + n];
    __bf16 h = (__bf16)v;
    th[t] = h;
    tl[t] = (__bf16)(v - (float)h);
}

// ---- split-bf16 MFMA GEMM: C = (relu?)(A @ W + bias) (+residual)
// A fp32 [nrows][256] split hi/lo during staging; W pre-transposed+split [n][k].
// tile 128x128, BK=32, 256 threads = 4 waves (2x2 of 64x64 each)
__global__ __launch_bounds__(256) void gemm_mfma(
    const float* __restrict__ A,
    const __bf16* __restrict__ Bth, const __bf16* __restrict__ Btl,
    const float* __restrict__ bias, const float* __restrict__ residual,
    float* __restrict__ C, int nrows, int do_relu) {
    __shared__ __attribute__((aligned(16))) __bf16 sAh[128 * 40];
    __shared__ __attribute__((aligned(16))) __bf16 sAl[128 * 40];
    __shared__ __attribute__((aligned(16))) __bf16 sBh[128 * 40];
    __shared__ __attribute__((aligned(16))) __bf16 sBl[128 * 40];

    int row0 = blockIdx.x * 128;
    int n0   = blockIdx.y * 128;
    int tid  = threadIdx.x;
    int lane = tid & 63, wave = tid >> 6;
    int wm = (wave >> 1) * 64, wn = (wave & 1) * 64;

    f32x4 acc[4][4];
    #pragma unroll
    for (int i = 0; i < 4; i++)
        #pragma unroll
        for (int j = 0; j < 4; j++) acc[i][j] = (f32x4)(0.f);

    int r  = tid >> 1;        // 0..127
    int hf = tid & 1;         // half: 16 elements each

    for (int kk = 0; kk < 256; kk += 32) {
        // ---- stage A (fp32 -> hi/lo bf16) ----
        {
            const float* ap = A + (size_t)(row0 + r) * 256 + kk + hf * 16;
            bool valid = (row0 + r) < nrows;
            #pragma unroll
            for (int q = 0; q < 4; q++) {
                float4 v = valid ? *(const float4*)(ap + q * 4)
                                 : make_float4(0.f, 0.f, 0.f, 0.f);
                bf16x4 hh, ll;
                hh[0] = (__bf16)v.x; ll[0] = (__bf16)(v.x - (float)hh[0]);
                hh[1] = (__bf16)v.y; ll[1] = (__bf16)(v.y - (float)hh[1]);
                hh[2] = (__bf16)v.z; ll[2] = (__bf16)(v.z - (float)hh[2]);
                hh[3] = (__bf16)v.w; ll[3] = (__bf16)(v.w - (float)hh[3]);
                *(bf16x4*)&sAh[r * 40 + hf * 16 + q * 4] = hh;
                *(bf16x4*)&sAl[r * 40 + hf * 16 + q * 4] = ll;
            }
        }
        // ---- stage B (pre-split bf16, straight copy) ----
        {
            size_t gb = (size_t)(n0 + r) * 256 + kk + hf * 16;
            uint4 vh0 = *(const uint4*)(Bth + gb);
            uint4 vh1 = *(const uint4*)(Bth + gb + 8);
            uint4 vl0 = *(const uint4*)(Btl + gb);
            uint4 vl1 = *(const uint4*)(Btl + gb + 8);
            *(uint4*)&sBh[r * 40 + hf * 16]     = vh0;
            *(uint4*)&sBh[r * 40 + hf * 16 + 8] = vh1;
            *(uint4*)&sBl[r * 40 + hf * 16]     = vl0;
            *(uint4*)&sBl[r * 40 + hf * 16 + 8] = vl1;
        }
        __syncthreads();

        int m_base = wm + (lane & 15);
        int n_base = wn + (lane & 15);
        int koff = (lane >> 4) * 8;
        bf16x8 ah[4], al[4], bh[4], bl[4];
        #pragma unroll
        for (int mt = 0; mt < 4; mt++) {
            ah[mt] = *(const bf16x8*)&sAh[(m_base + mt * 16) * 40 + koff];
            al[mt] = *(const bf16x8*)&sAl[(m_base + mt * 16) * 40 + koff];
        }
        #pragma unroll
        for (int nt = 0; nt < 4; nt++) {
            bh[nt] = *(const bf16x8*)&sBh[(n_base + nt * 16) * 40 + koff];
            bl[nt] = *(const bf16x8*)&sBl[(n_base + nt * 16) * 40 + koff];
        }
        #pragma unroll
        for (int mt = 0; mt < 4; mt++)
            #pragma unroll
            for (int nt = 0; nt < 4; nt++) {
                acc[mt][nt] = __builtin_amdgcn_mfma_f32_16x16x32_bf16(ah[mt], bh[nt], acc[mt][nt], 0, 0, 0);
                acc[mt][nt] = __builtin_amdgcn_mfma_f32_16x16x32_bf16(al[mt], bh[nt], acc[mt][nt], 0, 0, 0);
                acc[mt][nt] = __builtin_amdgcn_mfma_f32_16x16x32_bf16(ah[mt], bl[nt], acc[mt][nt], 0, 0, 0);
            }
        __syncthreads();
    }

    // ---- epilogue: C/D layout col=lane&15, row=(lane>>4)*4+reg ----
    #pragma unroll
    for (int mt = 0; mt < 4; mt++) {
        #pragma unroll
        for (int nt = 0; nt < 4; nt++) {
            int col = n0 + wn + nt * 16 + (lane & 15);
            #pragma unroll
            for (int rr = 0; rr < 4; rr++) {
                int row = row0 + wm + mt * 16 + (lane >> 4) * 4 + rr;
                if (row < nrows) {
                    float v = acc[mt][nt][rr] + bias[col];
                    if (do_relu) v = fmaxf(v, 0.f);
                    if (residual) v += residual[(size_t)row * 256 + col];
                    C[(size_t)row * 256 + col] = v;
                }
            }
        }
    }
}

// ---- CSR build ----
__global__ void hist_kernel(const int* __restrict__ recv, int* __restrict__ counts) {
    int t = blockIdx.x * 256 + threadIdx.x;
    if (t < M_EDGES) atomicAdd(&counts[recv[t]], 1);
}

__global__ void scan_kernel(const int* __restrict__ counts, int* __restrict__ offsets) {
    __shared__ int part[256];
    int t = threadIdx.x;
    const int per = (N_NODES + 255) / 256;
    int start = t * per;
    int end = min(start + per, N_NODES);
    int s = 0;
    for (int i = start; i < end; i++) s += counts[i];
    part[t] = s;
    __syncthreads();
    if (t == 0) {
        int acc = 0;
        for (int i = 0; i < 256; i++) { int v = part[i]; part[i] = acc; acc += v; }
    }
    __syncthreads();
    int acc = part[t];
    for (int i = start; i < end; i++) { offsets[i] = acc; acc += counts[i]; }
    if (end == N_NODES && start < N_NODES) offsets[N_NODES] = acc;
}

__global__ void fill_kernel(const int* __restrict__ recv, const int* __restrict__ offsets,
                            int* __restrict__ cursor, int* __restrict__ esorted) {
    int t = blockIdx.x * 256 + threadIdx.x;
    if (t < M_EDGES) {
        int r = recv[t];
        int pos = offsets[r] + atomicAdd(&cursor[r], 1);
        esorted[pos] = t;
    }
}

// ---- edge logits + global max ----
__global__ __launch_bounds__(256) void qk_kernel(
    const int* __restrict__ recv, const int* __restrict__ send,
    const float* __restrict__ Q, const float* __restrict__ K,
    float* __restrict__ qk, unsigned* __restrict__ gmax) {
    __shared__ unsigned smax;
    if (threadIdx.x == 0) smax = 0u;
    __syncthreads();
    int t = blockIdx.x * 256 + threadIdx.x;
    int e = t >> 3, h = t & 7;
    if (e < M_EDGES) {
        const float4* q = (const float4*)(Q + (size_t)recv[e] * 256 + h * 32);
        const float4* k = (const float4*)(K + (size_t)send[e] * 256 + h * 32);
        float dot = 0.f;
        #pragma unroll
        for (int i = 0; i < 8; i++) {
            float4 a = q[i], b = k[i];
            dot += a.x * b.x + a.y * b.y + a.z * b.z + a.w * b.w;
        }
        qk[(size_t)e * 8 + h] = dot;
        atomicMax(&smax, enc_ord(dot));
    }
    __syncthreads();
    if (threadIdx.x == 0) atomicMax(gmax, smax);
}

// ---- node aggregation v2: single pass, chunked LDS staging of (send, att) ----
__global__ __launch_bounds__(256) void node_agg_kernel(
    const int* __restrict__ send, const int* __restrict__ offsets,
    const int* __restrict__ esorted, const float* __restrict__ qk,
    const float* __restrict__ V, const unsigned* __restrict__ gmax,
    float* __restrict__ msg) {
    __shared__ int   s_send[32];
    __shared__ float s_att[32][8];
    int n = blockIdx.x;
    int c = threadIdx.x;          // c = h*32 + v
    int h = c >> 5;
    int off = offsets[n];
    int deg = offsets[n + 1] - off;
    float scale = 3.0f / dec_ord(*gmax);
    float sum = 0.f, acc = 0.f;
    for (int i0 = 0; i0 < deg; i0 += 32) {
        int cn = min(32, deg - i0);
        __syncthreads();
        if (c < cn) s_send[c] = send[esorted[off + i0 + c]];
        if (c < cn * 8) {
            int i = c >> 3, hh = c & 7;
            int e = esorted[off + i0 + i];
            s_att[i][hh] = __expf(qk[(size_t)e * 8 + hh] * scale);
        }
        __syncthreads();
        #pragma unroll 4
        for (int i = 0; i < cn; i++) {
            float a = s_att[i][h];
            sum += a;
            acc += a * V[(size_t)s_send[i] * 256 + c];
        }
    }
    float inv = (deg > 0) ? 1.0f / (sum * 5.65685424949238f) : 0.f;  // sqrt(32)
    msg[(size_t)n * 256 + c] = fmaxf(acc * inv, 0.f);
}

extern "C" void kernel_launch(void* const* d_in, const int* in_sizes, int n_in,
                              void* d_out, int out_size, void* d_ws, size_t ws_size,
                              hipStream_t stream) {
    const float* x    = (const float*)d_in[0];
    const int*   edge = (const int*)d_in[1];
    const int*   recv = edge;
    const int*   send = edge + M_EDGES;
    const float* Wk   = (const float*)d_in[2];
    const float* bk   = (const float*)d_in[3];
    const float* Wq   = (const float*)d_in[4];
    const float* bq   = (const float*)d_in[5];
    const float* Wv   = (const float*)d_in[6];
    const float* bv   = (const float*)d_in[7];
    const float* Wagg = (const float*)d_in[8];
    const float* bagg = (const float*)d_in[9];
    const float* Wff  = (const float*)d_in[10];
    const float* bff  = (const float*)d_in[11];
    float* out = (float*)d_out;

    // workspace layout (~184.4 MB)
    float* Kbuf   = (float*)d_ws;
    float* Qbuf   = Kbuf + (size_t)N_NODES * 256;
    float* Vbuf   = Qbuf + (size_t)N_NODES * 256;
    float* qkbuf  = Vbuf + (size_t)N_NODES * 256;
    int* counts   = (int*)(qkbuf + (size_t)M_EDGES * 8);
    int* cursor   = counts + N_NODES;
    int* offsets  = cursor + N_NODES;
    int* esorted  = offsets + N_NODES + 1;
    unsigned* gmax = (unsigned*)(esorted + M_EDGES);
    __bf16* wt    = (__bf16*)(gmax + 1);
    __bf16* WkH = wt;              __bf16* WkL = wt + 65536;
    __bf16* WqH = wt + 2 * 65536;  __bf16* WqL = wt + 3 * 65536;
    __bf16* WvH = wt + 4 * 65536;  __bf16* WvL = wt + 5 * 65536;
    __bf16* WaH = wt + 6 * 65536;  __bf16* WaL = wt + 7 * 65536;
    __bf16* WfH = wt + 8 * 65536;  __bf16* WfL = wt + 9 * 65536;
    float* msg    = Kbuf;  // reuse: K dead after qk_kernel
    float* hidden = Qbuf;  // reuse: Q dead after qk_kernel

    dim3 blk(256);
    dim3 gemm_grid((N_NODES + 127) / 128, 2);
    dim3 edge_grid((M_EDGES + 255) / 256);

    hipLaunchKernelGGL(init_kernel, dim3((N_NODES + 255) / 256), blk, 0, stream,
                       counts, cursor, gmax);
    // weight transpose + split (tiny)
    hipLaunchKernelGGL(wsplit_kernel, dim3(256), blk, 0, stream, Wk,   WkH, WkL);
    hipLaunchKernelGGL(wsplit_kernel, dim3(256), blk, 0, stream, Wq,   WqH, WqL);
    hipLaunchKernelGGL(wsplit_kernel, dim3(256), blk, 0, stream, Wv,   WvH, WvL);
    hipLaunchKernelGGL(wsplit_kernel, dim3(256), blk, 0, stream, Wagg, WaH, WaL);
    hipLaunchKernelGGL(wsplit_kernel, dim3(256), blk, 0, stream, Wff,  WfH, WfL);
    // projections (MFMA)
    hipLaunchKernelGGL(gemm_mfma, gemm_grid, blk, 0, stream, x, WkH, WkL, bk, nullptr, Kbuf, N_NODES, 0);
    hipLaunchKernelGGL(gemm_mfma, gemm_grid, blk, 0, stream, x, WqH, WqL, bq, nullptr, Qbuf, N_NODES, 0);
    hipLaunchKernelGGL(gemm_mfma, gemm_grid, blk, 0, stream, x, WvH, WvL, bv, nullptr, Vbuf, N_NODES, 0);
    // CSR build
    hipLaunchKernelGGL(hist_kernel, edge_grid, blk, 0, stream, recv, counts);
    hipLaunchKernelGGL(scan_kernel, dim3(1), blk, 0, stream, counts, offsets);
    hipLaunchKernelGGL(fill_kernel, edge_grid, blk, 0, stream, recv, offsets, cursor, esorted);
    // edge logits + global max
    hipLaunchKernelGGL(qk_kernel, dim3((M_EDGES * 8 + 255) / 256), blk, 0, stream,
                       recv, send, Qbuf, Kbuf, qkbuf, gmax);
    // segment softmax + aggregate
    hipLaunchKernelGGL(node_agg_kernel, dim3(N_NODES), blk, 0, stream,
                       send, offsets, esorted, qkbuf, Vbuf, gmax, msg);
    // output MLP (MFMA)
    hipLaunchKernelGGL(gemm_mfma, gemm_grid, blk, 0, stream, msg, WaH, WaL, bagg, nullptr, hidden, N_NODES, 1);
    hipLaunchKernelGGL(gemm_mfma, gemm_grid, blk, 0, stream, hidden, WfH, WfL, bff, x, out, N_NODES, 1);
}

// Round 3
// 938.910 us; speedup vs baseline: 1.6306x; 1.2135x over previous
//
#include <hip/hip_runtime.h>

#define N_NODES 50000
#define M_EDGES 800000

typedef __bf16 bf16x8 __attribute__((ext_vector_type(8)));
typedef __bf16 bf16x4 __attribute__((ext_vector_type(4)));
typedef float  f32x4  __attribute__((ext_vector_type(4)));

// ---- monotonic float<->unsigned encoding for atomicMax on floats ----
static __device__ __forceinline__ unsigned enc_ord(float f) {
    unsigned b = __float_as_uint(f);
    return (b & 0x80000000u) ? ~b : (b | 0x80000000u);
}
static __device__ __forceinline__ float dec_ord(unsigned u) {
    unsigned b = (u & 0x80000000u) ? (u ^ 0x80000000u) : ~u;
    return __uint_as_float(b);
}

// ---- init: zero CSR counters + gmax ----
__global__ void init_kernel(int* counts, int* cursor, unsigned* gmax) {
    int t = blockIdx.x * blockDim.x + threadIdx.x;
    if (t < N_NODES) { counts[t] = 0; cursor[t] = 0; }
    if (t == 0) *gmax = 0u;
}

// ---- weight transpose + hi/lo bf16 split: th[n*256+k] = bf16(W[k*256+n]) ----
__global__ void wsplit_kernel(const float* __restrict__ W,
                              __bf16* __restrict__ th, __bf16* __restrict__ tl) {
    int t = blockIdx.x * 256 + threadIdx.x;   // 65536 threads
    int n = t >> 8, k = t & 255;
    float v = W[(size_t)k * 256 + n];
    __bf16 h = (__bf16)v;
    th[t] = h;
    tl[t] = (__bf16)(v - (float)h);
}

// ---- split-bf16 MFMA GEMM: C = (relu?)(A @ W + bias) (+residual)
__global__ __launch_bounds__(256) void gemm_mfma(
    const float* __restrict__ A,
    const __bf16* __restrict__ Bth, const __bf16* __restrict__ Btl,
    const float* __restrict__ bias, const float* __restrict__ residual,
    float* __restrict__ C, int nrows, int do_relu) {
    __shared__ __attribute__((aligned(16))) __bf16 sAh[128 * 40];
    __shared__ __attribute__((aligned(16))) __bf16 sAl[128 * 40];
    __shared__ __attribute__((aligned(16))) __bf16 sBh[128 * 40];
    __shared__ __attribute__((aligned(16))) __bf16 sBl[128 * 40];

    int row0 = blockIdx.x * 128;
    int n0   = blockIdx.y * 128;
    int tid  = threadIdx.x;
    int lane = tid & 63, wave = tid >> 6;
    int wm = (wave >> 1) * 64, wn = (wave & 1) * 64;

    f32x4 acc[4][4];
    #pragma unroll
    for (int i = 0; i < 4; i++)
        #pragma unroll
        for (int j = 0; j < 4; j++) acc[i][j] = (f32x4)(0.f);

    int r  = tid >> 1;
    int hf = tid & 1;

    for (int kk = 0; kk < 256; kk += 32) {
        {
            const float* ap = A + (size_t)(row0 + r) * 256 + kk + hf * 16;
            bool valid = (row0 + r) < nrows;
            #pragma unroll
            for (int q = 0; q < 4; q++) {
                float4 v = valid ? *(const float4*)(ap + q * 4)
                                 : make_float4(0.f, 0.f, 0.f, 0.f);
                bf16x4 hh, ll;
                hh[0] = (__bf16)v.x; ll[0] = (__bf16)(v.x - (float)hh[0]);
                hh[1] = (__bf16)v.y; ll[1] = (__bf16)(v.y - (float)hh[1]);
                hh[2] = (__bf16)v.z; ll[2] = (__bf16)(v.z - (float)hh[2]);
                hh[3] = (__bf16)v.w; ll[3] = (__bf16)(v.w - (float)hh[3]);
                *(bf16x4*)&sAh[r * 40 + hf * 16 + q * 4] = hh;
                *(bf16x4*)&sAl[r * 40 + hf * 16 + q * 4] = ll;
            }
        }
        {
            size_t gb = (size_t)(n0 + r) * 256 + kk + hf * 16;
            uint4 vh0 = *(const uint4*)(Bth + gb);
            uint4 vh1 = *(const uint4*)(Bth + gb + 8);
            uint4 vl0 = *(const uint4*)(Btl + gb);
            uint4 vl1 = *(const uint4*)(Btl + gb + 8);
            *(uint4*)&sBh[r * 40 + hf * 16]     = vh0;
            *(uint4*)&sBh[r * 40 + hf * 16 + 8] = vh1;
            *(uint4*)&sBl[r * 40 + hf * 16]     = vl0;
            *(uint4*)&sBl[r * 40 + hf * 16 + 8] = vl1;
        }
        __syncthreads();

        int m_base = wm + (lane & 15);
        int n_base = wn + (lane & 15);
        int koff = (lane >> 4) * 8;
        bf16x8 ah[4], al[4], bh[4], bl[4];
        #pragma unroll
        for (int mt = 0; mt < 4; mt++) {
            ah[mt] = *(const bf16x8*)&sAh[(m_base + mt * 16) * 40 + koff];
            al[mt] = *(const bf16x8*)&sAl[(m_base + mt * 16) * 40 + koff];
        }
        #pragma unroll
        for (int nt = 0; nt < 4; nt++) {
            bh[nt] = *(const bf16x8*)&sBh[(n_base + nt * 16) * 40 + koff];
            bl[nt] = *(const bf16x8*)&sBl[(n_base + nt * 16) * 40 + koff];
        }
        #pragma unroll
        for (int mt = 0; mt < 4; mt++)
            #pragma unroll
            for (int nt = 0; nt < 4; nt++) {
                acc[mt][nt] = __builtin_amdgcn_mfma_f32_16x16x32_bf16(ah[mt], bh[nt], acc[mt][nt], 0, 0, 0);
                acc[mt][nt] = __builtin_amdgcn_mfma_f32_16x16x32_bf16(al[mt], bh[nt], acc[mt][nt], 0, 0, 0);
                acc[mt][nt] = __builtin_amdgcn_mfma_f32_16x16x32_bf16(ah[mt], bl[nt], acc[mt][nt], 0, 0, 0);
            }
        __syncthreads();
    }

    #pragma unroll
    for (int mt = 0; mt < 4; mt++) {
        #pragma unroll
        for (int nt = 0; nt < 4; nt++) {
            int col = n0 + wn + nt * 16 + (lane & 15);
            #pragma unroll
            for (int rr = 0; rr < 4; rr++) {
                int row = row0 + wm + mt * 16 + (lane >> 4) * 4 + rr;
                if (row < nrows) {
                    float v = acc[mt][nt][rr] + bias[col];
                    if (do_relu) v = fmaxf(v, 0.f);
                    if (residual) v += residual[(size_t)row * 256 + col];
                    C[(size_t)row * 256 + col] = v;
                }
            }
        }
    }
}

// ---- CSR build ----
__global__ void hist_kernel(const int* __restrict__ recv, int* __restrict__ counts) {
    int t = blockIdx.x * 256 + threadIdx.x;
    if (t < M_EDGES) atomicAdd(&counts[recv[t]], 1);
}

__global__ void scan_kernel(const int* __restrict__ counts, int* __restrict__ offsets) {
    __shared__ int part[256];
    int t = threadIdx.x;
    const int per = (N_NODES + 255) / 256;
    int start = t * per;
    int end = min(start + per, N_NODES);
    int s = 0;
    for (int i = start; i < end; i++) s += counts[i];
    part[t] = s;
    __syncthreads();
    if (t == 0) {
        int acc = 0;
        for (int i = 0; i < 256; i++) { int v = part[i]; part[i] = acc; acc += v; }
    }
    __syncthreads();
    int acc = part[t];
    for (int i = start; i < end; i++) { offsets[i] = acc; acc += counts[i]; }
    if (end == N_NODES && start < N_NODES) offsets[N_NODES] = acc;
}

// ---- CSR fill: ssorted[pos] = send[e], receiver-sorted ----
__global__ void fill_kernel(const int* __restrict__ recv, const int* __restrict__ send,
                            const int* __restrict__ offsets,
                            int* __restrict__ cursor, int* __restrict__ ssorted) {
    int t = blockIdx.x * 256 + threadIdx.x;
    if (t < M_EDGES) {
        int r = recv[t];
        int pos = offsets[r] + atomicAdd(&cursor[r], 1);
        ssorted[pos] = send[t];
    }
}

// ---- edge logits in CSR order: one wave per node, Q row in registers ----
__global__ __launch_bounds__(256) void qk_csr_kernel(
    const int* __restrict__ offsets, const int* __restrict__ ssorted,
    const float* __restrict__ Q, const float* __restrict__ K,
    float* __restrict__ qks, unsigned* __restrict__ gmax) {
    __shared__ float swmax[4];
    int wave = threadIdx.x >> 6, lane = threadIdx.x & 63;
    int n = blockIdx.x * 4 + wave;
    float wmax = -INFINITY;
    if (n < N_NODES) {
        int off = offsets[n], deg = offsets[n + 1] - off;
        float4 q = *(const float4*)(Q + (size_t)n * 256 + lane * 4);
        if (deg > 0) {
            int s0 = ssorted[off];
            float4 kv = *(const float4*)(K + (size_t)s0 * 256 + lane * 4);
            for (int j = 0; j < deg; j++) {
                float4 kc = kv;
                if (j + 1 < deg) {
                    int s1 = ssorted[off + j + 1];
                    kv = *(const float4*)(K + (size_t)s1 * 256 + lane * 4);
                }
                float d = q.x * kc.x + q.y * kc.y + q.z * kc.z + q.w * kc.w;
                d += __shfl_xor(d, 1);
                d += __shfl_xor(d, 2);
                d += __shfl_xor(d, 4);   // all 8 lanes of the head group hold d
                if ((lane & 7) == 0) qks[(size_t)(off + j) * 8 + (lane >> 3)] = d;
                wmax = fmaxf(wmax, d);
            }
        }
    }
    wmax = fmaxf(wmax, __shfl_xor(wmax, 8));
    wmax = fmaxf(wmax, __shfl_xor(wmax, 16));
    wmax = fmaxf(wmax, __shfl_xor(wmax, 32));
    if (lane == 0) swmax[wave] = wmax;
    __syncthreads();
    if (threadIdx.x == 0) {
        float m = fmaxf(fmaxf(swmax[0], swmax[1]), fmaxf(swmax[2], swmax[3]));
        if (m > -INFINITY) atomicMax(gmax, enc_ord(m));
    }
}

// ---- node aggregation: single pass, chunked LDS staging, sequential qk ----
__global__ __launch_bounds__(256) void node_agg_kernel(
    const int* __restrict__ offsets, const int* __restrict__ ssorted,
    const float* __restrict__ qks, const float* __restrict__ V,
    const unsigned* __restrict__ gmax, float* __restrict__ msg) {
    __shared__ int   s_send[32];
    __shared__ float s_att[32][8];
    int n = blockIdx.x;
    int c = threadIdx.x;          // c = h*32 + v
    int h = c >> 5;
    int off = offsets[n];
    int deg = offsets[n + 1] - off;
    float scale = 3.0f / dec_ord(*gmax);
    float sum = 0.f, acc = 0.f;
    for (int i0 = 0; i0 < deg; i0 += 32) {
        int cn = min(32, deg - i0);
        __syncthreads();
        if (c < cn) s_send[c] = ssorted[off + i0 + c];
        if (c < cn * 8) {
            int i = c >> 3, hh = c & 7;
            s_att[i][hh] = __expf(qks[(size_t)(off + i0) * 8 + c] * scale);
        }
        __syncthreads();
        #pragma unroll 4
        for (int i = 0; i < cn; i++) {
            float a = s_att[i][h];
            sum += a;
            acc += a * V[(size_t)s_send[i] * 256 + c];
        }
    }
    float inv = (deg > 0) ? 1.0f / (sum * 5.65685424949238f) : 0.f;  // sqrt(32)
    msg[(size_t)n * 256 + c] = fmaxf(acc * inv, 0.f);
}

extern "C" void kernel_launch(void* const* d_in, const int* in_sizes, int n_in,
                              void* d_out, int out_size, void* d_ws, size_t ws_size,
                              hipStream_t stream) {
    const float* x    = (const float*)d_in[0];
    const int*   edge = (const int*)d_in[1];
    const int*   recv = edge;
    const int*   send = edge + M_EDGES;
    const float* Wk   = (const float*)d_in[2];
    const float* bk   = (const float*)d_in[3];
    const float* Wq   = (const float*)d_in[4];
    const float* bq   = (const float*)d_in[5];
    const float* Wv   = (const float*)d_in[6];
    const float* bv   = (const float*)d_in[7];
    const float* Wagg = (const float*)d_in[8];
    const float* bagg = (const float*)d_in[9];
    const float* Wff  = (const float*)d_in[10];
    const float* bff  = (const float*)d_in[11];
    float* out = (float*)d_out;

    float* Kbuf   = (float*)d_ws;
    float* Qbuf   = Kbuf + (size_t)N_NODES * 256;
    float* Vbuf   = Qbuf + (size_t)N_NODES * 256;
    float* qks    = Vbuf + (size_t)N_NODES * 256;       // receiver-sorted logits
    int* counts   = (int*)(qks + (size_t)M_EDGES * 8);
    int* cursor   = counts + N_NODES;
    int* offsets  = cursor + N_NODES;
    int* ssorted  = offsets + N_NODES + 1;
    unsigned* gmax = (unsigned*)(ssorted + M_EDGES);
    __bf16* wt    = (__bf16*)(gmax + 1);
    __bf16* WkH = wt;              __bf16* WkL = wt + 65536;
    __bf16* WqH = wt + 2 * 65536;  __bf16* WqL = wt + 3 * 65536;
    __bf16* WvH = wt + 4 * 65536;  __bf16* WvL = wt + 5 * 65536;
    __bf16* WaH = wt + 6 * 65536;  __bf16* WaL = wt + 7 * 65536;
    __bf16* WfH = wt + 8 * 65536;  __bf16* WfL = wt + 9 * 65536;
    float* msg    = Kbuf;  // reuse: K dead after qk_csr_kernel
    float* hidden = Qbuf;  // reuse: Q dead after qk_csr_kernel

    dim3 blk(256);
    dim3 gemm_grid((N_NODES + 127) / 128, 2);
    dim3 edge_grid((M_EDGES + 255) / 256);

    hipLaunchKernelGGL(init_kernel, dim3((N_NODES + 255) / 256), blk, 0, stream,
                       counts, cursor, gmax);
    hipLaunchKernelGGL(wsplit_kernel, dim3(256), blk, 0, stream, Wk,   WkH, WkL);
    hipLaunchKernelGGL(wsplit_kernel, dim3(256), blk, 0, stream, Wq,   WqH, WqL);
    hipLaunchKernelGGL(wsplit_kernel, dim3(256), blk, 0, stream, Wv,   WvH, WvL);
    hipLaunchKernelGGL(wsplit_kernel, dim3(256), blk, 0, stream, Wagg, WaH, WaL);
    hipLaunchKernelGGL(wsplit_kernel, dim3(256), blk, 0, stream, Wff,  WfH, WfL);
    // projections (MFMA)
    hipLaunchKernelGGL(gemm_mfma, gemm_grid, blk, 0, stream, x, WkH, WkL, bk, nullptr, Kbuf, N_NODES, 0);
    hipLaunchKernelGGL(gemm_mfma, gemm_grid, blk, 0, stream, x, WqH, WqL, bq, nullptr, Qbuf, N_NODES, 0);
    hipLaunchKernelGGL(gemm_mfma, gemm_grid, blk, 0, stream, x, WvH, WvL, bv, nullptr, Vbuf, N_NODES, 0);
    // CSR build
    hipLaunchKernelGGL(hist_kernel, edge_grid, blk, 0, stream, recv, counts);
    hipLaunchKernelGGL(scan_kernel, dim3(1), blk, 0, stream, counts, offsets);
    hipLaunchKernelGGL(fill_kernel, edge_grid, blk, 0, stream, recv, send, offsets, cursor, ssorted);
    // edge logits in CSR order + global max
    hipLaunchKernelGGL(qk_csr_kernel, dim3((N_NODES + 3) / 4), blk, 0, stream,
                       offsets, ssorted, Qbuf, Kbuf, qks, gmax);
    // segment softmax + aggregate
    hipLaunchKernelGGL(node_agg_kernel, dim3(N_NODES), blk, 0, stream,
                       offsets, ssorted, qks, Vbuf, gmax, msg);
    // output MLP (MFMA)
    hipLaunchKernelGGL(gemm_mfma, gemm_grid, blk, 0, stream, msg, WaH, WaL, bagg, nullptr, hidden, N_NODES, 1);
    hipLaunchKernelGGL(gemm_mfma, gemm_grid, blk, 0, stream, hidden, WfH, WfL, bff, x, out, N_NODES, 1);
}

// Round 4
// 902.116 us; speedup vs baseline: 1.6971x; 1.0408x over previous
//
#include <hip/hip_runtime.h>

#define N_NODES 50000
#define M_EDGES 800000

typedef __bf16 bf16x8 __attribute__((ext_vector_type(8)));
typedef __bf16 bf16x4 __attribute__((ext_vector_type(4)));
typedef float  f32x4  __attribute__((ext_vector_type(4)));

static __device__ __forceinline__ unsigned enc_ord(float f) {
    unsigned b = __float_as_uint(f);
    return (b & 0x80000000u) ? ~b : (b | 0x80000000u);
}
static __device__ __forceinline__ float dec_ord(unsigned u) {
    unsigned b = (u & 0x80000000u) ? (u ^ 0x80000000u) : ~u;
    return __uint_as_float(b);
}
static __device__ __forceinline__ float bf2f(unsigned short u) {
    return __uint_as_float(((unsigned)u) << 16);
}

__global__ void init_kernel(int* counts, int* cursor, unsigned* gmax) {
    int t = blockIdx.x * blockDim.x + threadIdx.x;
    if (t < N_NODES) { counts[t] = 0; cursor[t] = 0; }
    if (t == 0) *gmax = 0u;
}

__global__ void wsplit_kernel(const float* __restrict__ W,
                              __bf16* __restrict__ th, __bf16* __restrict__ tl) {
    int t = blockIdx.x * 256 + threadIdx.x;
    int n = t >> 8, k = t & 255;
    float v = W[(size_t)k * 256 + n];
    __bf16 h = (__bf16)v;
    th[t] = h;
    tl[t] = (__bf16)(v - (float)h);
}

// ---- split-bf16 MFMA GEMM. Output: fp32 C (with optional relu/residual) OR bf16 Cb.
__global__ __launch_bounds__(256) void gemm_mfma(
    const float* __restrict__ A,
    const __bf16* __restrict__ Bth, const __bf16* __restrict__ Btl,
    const float* __restrict__ bias, const float* __restrict__ residual,
    float* __restrict__ C, __bf16* __restrict__ Cb, int nrows, int do_relu) {
    __shared__ __attribute__((aligned(16))) __bf16 sAh[128 * 40];
    __shared__ __attribute__((aligned(16))) __bf16 sAl[128 * 40];
    __shared__ __attribute__((aligned(16))) __bf16 sBh[128 * 40];
    __shared__ __attribute__((aligned(16))) __bf16 sBl[128 * 40];

    int row0 = blockIdx.x * 128;
    int n0   = blockIdx.y * 128;
    int tid  = threadIdx.x;
    int lane = tid & 63, wave = tid >> 6;
    int wm = (wave >> 1) * 64, wn = (wave & 1) * 64;

    f32x4 acc[4][4];
    #pragma unroll
    for (int i = 0; i < 4; i++)
        #pragma unroll
        for (int j = 0; j < 4; j++) acc[i][j] = (f32x4)(0.f);

    int r  = tid >> 1;
    int hf = tid & 1;

    for (int kk = 0; kk < 256; kk += 32) {
        {
            const float* ap = A + (size_t)(row0 + r) * 256 + kk + hf * 16;
            bool valid = (row0 + r) < nrows;
            #pragma unroll
            for (int q = 0; q < 4; q++) {
                float4 v = valid ? *(const float4*)(ap + q * 4)
                                 : make_float4(0.f, 0.f, 0.f, 0.f);
                bf16x4 hh, ll;
                hh[0] = (__bf16)v.x; ll[0] = (__bf16)(v.x - (float)hh[0]);
                hh[1] = (__bf16)v.y; ll[1] = (__bf16)(v.y - (float)hh[1]);
                hh[2] = (__bf16)v.z; ll[2] = (__bf16)(v.z - (float)hh[2]);
                hh[3] = (__bf16)v.w; ll[3] = (__bf16)(v.w - (float)hh[3]);
                *(bf16x4*)&sAh[r * 40 + hf * 16 + q * 4] = hh;
                *(bf16x4*)&sAl[r * 40 + hf * 16 + q * 4] = ll;
            }
        }
        {
            size_t gb = (size_t)(n0 + r) * 256 + kk + hf * 16;
            uint4 vh0 = *(const uint4*)(Bth + gb);
            uint4 vh1 = *(const uint4*)(Bth + gb + 8);
            uint4 vl0 = *(const uint4*)(Btl + gb);
            uint4 vl1 = *(const uint4*)(Btl + gb + 8);
            *(uint4*)&sBh[r * 40 + hf * 16]     = vh0;
            *(uint4*)&sBh[r * 40 + hf * 16 + 8] = vh1;
            *(uint4*)&sBl[r * 40 + hf * 16]     = vl0;
            *(uint4*)&sBl[r * 40 + hf * 16 + 8] = vl1;
        }
        __syncthreads();

        int m_base = wm + (lane & 15);
        int n_base = wn + (lane & 15);
        int koff = (lane >> 4) * 8;
        bf16x8 ah[4], al[4], bh[4], bl[4];
        #pragma unroll
        for (int mt = 0; mt < 4; mt++) {
            ah[mt] = *(const bf16x8*)&sAh[(m_base + mt * 16) * 40 + koff];
            al[mt] = *(const bf16x8*)&sAl[(m_base + mt * 16) * 40 + koff];
        }
        #pragma unroll
        for (int nt = 0; nt < 4; nt++) {
            bh[nt] = *(const bf16x8*)&sBh[(n_base + nt * 16) * 40 + koff];
            bl[nt] = *(const bf16x8*)&sBl[(n_base + nt * 16) * 40 + koff];
        }
        #pragma unroll
        for (int mt = 0; mt < 4; mt++)
            #pragma unroll
            for (int nt = 0; nt < 4; nt++) {
                acc[mt][nt] = __builtin_amdgcn_mfma_f32_16x16x32_bf16(ah[mt], bh[nt], acc[mt][nt], 0, 0, 0);
                acc[mt][nt] = __builtin_amdgcn_mfma_f32_16x16x32_bf16(al[mt], bh[nt], acc[mt][nt], 0, 0, 0);
                acc[mt][nt] = __builtin_amdgcn_mfma_f32_16x16x32_bf16(ah[mt], bl[nt], acc[mt][nt], 0, 0, 0);
            }
        __syncthreads();
    }

    #pragma unroll
    for (int mt = 0; mt < 4; mt++) {
        #pragma unroll
        for (int nt = 0; nt < 4; nt++) {
            int col = n0 + wn + nt * 16 + (lane & 15);
            #pragma unroll
            for (int rr = 0; rr < 4; rr++) {
                int row = row0 + wm + mt * 16 + (lane >> 4) * 4 + rr;
                if (row < nrows) {
                    float v = acc[mt][nt][rr] + bias[col];
                    if (do_relu) v = fmaxf(v, 0.f);
                    if (Cb) {
                        Cb[(size_t)row * 256 + col] = (__bf16)v;
                    } else {
                        if (residual) v += residual[(size_t)row * 256 + col];
                        C[(size_t)row * 256 + col] = v;
                    }
                }
            }
        }
    }
}

// ---- CSR build ----
__global__ void hist_kernel(const int* __restrict__ recv, int* __restrict__ counts) {
    int t = blockIdx.x * 256 + threadIdx.x;
    if (t < M_EDGES) atomicAdd(&counts[recv[t]], 1);
}

__global__ void scan_kernel(const int* __restrict__ counts, int* __restrict__ offsets) {
    __shared__ int part[256];
    int t = threadIdx.x;
    const int per = (N_NODES + 255) / 256;
    int start = t * per;
    int end = min(start + per, N_NODES);
    int s = 0;
    for (int i = start; i < end; i++) s += counts[i];
    part[t] = s;
    __syncthreads();
    if (t == 0) {
        int acc = 0;
        for (int i = 0; i < 256; i++) { int v = part[i]; part[i] = acc; acc += v; }
    }
    __syncthreads();
    int acc = part[t];
    for (int i = start; i < end; i++) { offsets[i] = acc; acc += counts[i]; }
    if (end == N_NODES && start < N_NODES) offsets[N_NODES] = acc;
}

__global__ void fill_kernel(const int* __restrict__ recv, const int* __restrict__ send,
                            const int* __restrict__ offsets,
                            int* __restrict__ cursor, int* __restrict__ ssorted) {
    int t = blockIdx.x * 256 + threadIdx.x;
    if (t < M_EDGES) {
        int r = recv[t];
        int pos = offsets[r] + atomicAdd(&cursor[r], 1);
        ssorted[pos] = send[t];
    }
}

// ---- edge logits in CSR order, bf16 K gather (512B rows) ----
__global__ __launch_bounds__(256) void qk_csr_kernel(
    const int* __restrict__ offsets, const int* __restrict__ ssorted,
    const float* __restrict__ Q, const unsigned short* __restrict__ Kb,
    float* __restrict__ qks, unsigned* __restrict__ gmax) {
    __shared__ float swmax[4];
    int wave = threadIdx.x >> 6, lane = threadIdx.x & 63;
    int n = blockIdx.x * 4 + wave;
    float wmax = -INFINITY;
    if (n < N_NODES) {
        int off = offsets[n], deg = offsets[n + 1] - off;
        float4 q = *(const float4*)(Q + (size_t)n * 256 + lane * 4);
        if (deg > 0) {
            int s0 = ssorted[off];
            ushort4 kv = *(const ushort4*)(Kb + (size_t)s0 * 256 + lane * 4);
            for (int j = 0; j < deg; j++) {
                ushort4 kc = kv;
                if (j + 1 < deg) {
                    int s1 = ssorted[off + j + 1];
                    kv = *(const ushort4*)(Kb + (size_t)s1 * 256 + lane * 4);
                }
                float d = q.x * bf2f(kc.x) + q.y * bf2f(kc.y)
                        + q.z * bf2f(kc.z) + q.w * bf2f(kc.w);
                d += __shfl_xor(d, 1);
                d += __shfl_xor(d, 2);
                d += __shfl_xor(d, 4);
                if ((lane & 7) == 0) qks[(size_t)(off + j) * 8 + (lane >> 3)] = d;
                wmax = fmaxf(wmax, d);
            }
        }
    }
    wmax = fmaxf(wmax, __shfl_xor(wmax, 8));
    wmax = fmaxf(wmax, __shfl_xor(wmax, 16));
    wmax = fmaxf(wmax, __shfl_xor(wmax, 32));
    if (lane == 0) swmax[wave] = wmax;
    __syncthreads();
    if (threadIdx.x == 0) {
        float m = fmaxf(fmaxf(swmax[0], swmax[1]), fmaxf(swmax[2], swmax[3]));
        if (m > -INFINITY) atomicMax(gmax, enc_ord(m));
    }
}

// ---- node aggregation, bf16 V gather (512B rows) ----
__global__ __launch_bounds__(256) void node_agg_kernel(
    const int* __restrict__ offsets, const int* __restrict__ ssorted,
    const float* __restrict__ qks, const unsigned short* __restrict__ Vb,
    const unsigned* __restrict__ gmax, float* __restrict__ msg) {
    __shared__ int   s_send[32];
    __shared__ float s_att[32][8];
    int n = blockIdx.x;
    int c = threadIdx.x;          // c = h*32 + v
    int h = c >> 5;
    int off = offsets[n];
    int deg = offsets[n + 1] - off;
    float scale = 3.0f / dec_ord(*gmax);
    float sum = 0.f, acc = 0.f;
    for (int i0 = 0; i0 < deg; i0 += 32) {
        int cn = min(32, deg - i0);
        __syncthreads();
        if (c < cn) s_send[c] = ssorted[off + i0 + c];
        if (c < cn * 8) {
            s_att[c >> 3][c & 7] = __expf(qks[(size_t)(off + i0) * 8 + c] * scale);
        }
        __syncthreads();
        #pragma unroll 4
        for (int i = 0; i < cn; i++) {
            float a = s_att[i][h];
            sum += a;
            acc += a * bf2f(Vb[(size_t)s_send[i] * 256 + c]);
        }
    }
    float inv = (deg > 0) ? 1.0f / (sum * 5.65685424949238f) : 0.f;  // sqrt(32)
    msg[(size_t)n * 256 + c] = fmaxf(acc * inv, 0.f);
}

extern "C" void kernel_launch(void* const* d_in, const int* in_sizes, int n_in,
                              void* d_out, int out_size, void* d_ws, size_t ws_size,
                              hipStream_t stream) {
    const float* x    = (const float*)d_in[0];
    const int*   edge = (const int*)d_in[1];
    const int*   recv = edge;
    const int*   send = edge + M_EDGES;
    const float* Wk   = (const float*)d_in[2];
    const float* bk   = (const float*)d_in[3];
    const float* Wq   = (const float*)d_in[4];
    const float* bq   = (const float*)d_in[5];
    const float* Wv   = (const float*)d_in[6];
    const float* bv   = (const float*)d_in[7];
    const float* Wagg = (const float*)d_in[8];
    const float* bagg = (const float*)d_in[9];
    const float* Wff  = (const float*)d_in[10];
    const float* bff  = (const float*)d_in[11];
    float* out = (float*)d_out;

    // workspace layout (~186 MB)
    float*  Qbuf  = (float*)d_ws;                          // 51.2 MB
    float*  msg   = Qbuf + (size_t)N_NODES * 256;          // 51.2 MB
    float*  qks   = msg + (size_t)N_NODES * 256;           // 25.6 MB
    __bf16* Kbf   = (__bf16*)(qks + (size_t)M_EDGES * 8);  // 25.6 MB
    __bf16* Vbf   = Kbf + (size_t)N_NODES * 256;           // 25.6 MB
    int* counts   = (int*)(Vbf + (size_t)N_NODES * 256);
    int* cursor   = counts + N_NODES;
    int* offsets  = cursor + N_NODES;
    int* ssorted  = offsets + N_NODES + 1;                 // 3.2 MB
    unsigned* gmax = (unsigned*)(ssorted + M_EDGES);
    __bf16* wt    = (__bf16*)(gmax + 1);                   // 2.6 MB
    __bf16* WkH = wt;              __bf16* WkL = wt + 65536;
    __bf16* WqH = wt + 2 * 65536;  __bf16* WqL = wt + 3 * 65536;
    __bf16* WvH = wt + 4 * 65536;  __bf16* WvL = wt + 5 * 65536;
    __bf16* WaH = wt + 6 * 65536;  __bf16* WaL = wt + 7 * 65536;
    __bf16* WfH = wt + 8 * 65536;  __bf16* WfL = wt + 9 * 65536;
    float* hidden = Qbuf;  // reuse: Q dead after qk_csr_kernel

    dim3 blk(256);
    dim3 gemm_grid((N_NODES + 127) / 128, 2);
    dim3 edge_grid((M_EDGES + 255) / 256);

    hipLaunchKernelGGL(init_kernel, dim3((N_NODES + 255) / 256), blk, 0, stream,
                       counts, cursor, gmax);
    hipLaunchKernelGGL(wsplit_kernel, dim3(256), blk, 0, stream, Wk,   WkH, WkL);
    hipLaunchKernelGGL(wsplit_kernel, dim3(256), blk, 0, stream, Wq,   WqH, WqL);
    hipLaunchKernelGGL(wsplit_kernel, dim3(256), blk, 0, stream, Wv,   WvH, WvL);
    hipLaunchKernelGGL(wsplit_kernel, dim3(256), blk, 0, stream, Wagg, WaH, WaL);
    hipLaunchKernelGGL(wsplit_kernel, dim3(256), blk, 0, stream, Wff,  WfH, WfL);
    // projections (MFMA); K,V emitted as bf16, Q fp32
    hipLaunchKernelGGL(gemm_mfma, gemm_grid, blk, 0, stream, x, WkH, WkL, bk, nullptr,
                       (float*)nullptr, Kbf, N_NODES, 0);
    hipLaunchKernelGGL(gemm_mfma, gemm_grid, blk, 0, stream, x, WqH, WqL, bq, nullptr,
                       Qbuf, (__bf16*)nullptr, N_NODES, 0);
    hipLaunchKernelGGL(gemm_mfma, gemm_grid, blk, 0, stream, x, WvH, WvL, bv, nullptr,
                       (float*)nullptr, Vbf, N_NODES, 0);
    // CSR build
    hipLaunchKernelGGL(hist_kernel, edge_grid, blk, 0, stream, recv, counts);
    hipLaunchKernelGGL(scan_kernel, dim3(1), blk, 0, stream, counts, offsets);
    hipLaunchKernelGGL(fill_kernel, edge_grid, blk, 0, stream, recv, send, offsets, cursor, ssorted);
    // edge logits + global max
    hipLaunchKernelGGL(qk_csr_kernel, dim3((N_NODES + 3) / 4), blk, 0, stream,
                       offsets, ssorted, Qbuf, (const unsigned short*)Kbf, qks, gmax);
    // segment softmax + aggregate
    hipLaunchKernelGGL(node_agg_kernel, dim3(N_NODES), blk, 0, stream,
                       offsets, ssorted, qks, (const unsigned short*)Vbf, gmax, msg);
    // output MLP (MFMA)
    hipLaunchKernelGGL(gemm_mfma, gemm_grid, blk, 0, stream, msg, WaH, WaL, bagg, nullptr,
                       hidden, (__bf16*)nullptr, N_NODES, 1);
    hipLaunchKernelGGL(gemm_mfma, gemm_grid, blk, 0, stream, hidden, WfH, WfL, bff, x,
                       out, (__bf16*)nullptr, N_NODES, 1);
}

// Round 5
// 885.356 us; speedup vs baseline: 1.7293x; 1.0189x over previous
//
#include <hip/hip_runtime.h>

#define N_NODES 50000
#define M_EDGES 800000

typedef __bf16 bf16x8 __attribute__((ext_vector_type(8)));
typedef __bf16 bf16x4 __attribute__((ext_vector_type(4)));
typedef float  f32x4  __attribute__((ext_vector_type(4)));

static __device__ __forceinline__ unsigned enc_ord(float f) {
    unsigned b = __float_as_uint(f);
    return (b & 0x80000000u) ? ~b : (b | 0x80000000u);
}
static __device__ __forceinline__ float dec_ord(unsigned u) {
    unsigned b = (u & 0x80000000u) ? (u ^ 0x80000000u) : ~u;
    return __uint_as_float(b);
}
// bf16 pair packed in a uint: lo = bits[15:0], hi = bits[31:16]
static __device__ __forceinline__ float bflo(unsigned u) { return __uint_as_float(u << 16); }
static __device__ __forceinline__ float bfhi(unsigned u) { return __uint_as_float(u & 0xffff0000u); }

__global__ void init_kernel(int* counts, int* cursor, unsigned* gmax) {
    int t = blockIdx.x * blockDim.x + threadIdx.x;
    if (t < N_NODES) { counts[t] = 0; cursor[t] = 0; }
    if (t == 0) *gmax = 0u;
}

__global__ void wsplit_kernel(const float* __restrict__ W,
                              __bf16* __restrict__ th, __bf16* __restrict__ tl) {
    int t = blockIdx.x * 256 + threadIdx.x;
    int n = t >> 8, k = t & 255;
    float v = W[(size_t)k * 256 + n];
    __bf16 h = (__bf16)v;
    th[t] = h;
    tl[t] = (__bf16)(v - (float)h);
}

// ---- split-bf16 MFMA GEMM. Output: fp32 C (with optional relu/residual) OR bf16 Cb.
__global__ __launch_bounds__(256) void gemm_mfma(
    const float* __restrict__ A,
    const __bf16* __restrict__ Bth, const __bf16* __restrict__ Btl,
    const float* __restrict__ bias, const float* __restrict__ residual,
    float* __restrict__ C, __bf16* __restrict__ Cb, int nrows, int do_relu) {
    __shared__ __attribute__((aligned(16))) __bf16 sAh[128 * 40];
    __shared__ __attribute__((aligned(16))) __bf16 sAl[128 * 40];
    __shared__ __attribute__((aligned(16))) __bf16 sBh[128 * 40];
    __shared__ __attribute__((aligned(16))) __bf16 sBl[128 * 40];

    int row0 = blockIdx.x * 128;
    int n0   = blockIdx.y * 128;
    int tid  = threadIdx.x;
    int lane = tid & 63, wave = tid >> 6;
    int wm = (wave >> 1) * 64, wn = (wave & 1) * 64;

    f32x4 acc[4][4];
    #pragma unroll
    for (int i = 0; i < 4; i++)
        #pragma unroll
        for (int j = 0; j < 4; j++) acc[i][j] = (f32x4)(0.f);

    int r  = tid >> 1;
    int hf = tid & 1;

    for (int kk = 0; kk < 256; kk += 32) {
        {
            const float* ap = A + (size_t)(row0 + r) * 256 + kk + hf * 16;
            bool valid = (row0 + r) < nrows;
            #pragma unroll
            for (int q = 0; q < 4; q++) {
                float4 v = valid ? *(const float4*)(ap + q * 4)
                                 : make_float4(0.f, 0.f, 0.f, 0.f);
                bf16x4 hh, ll;
                hh[0] = (__bf16)v.x; ll[0] = (__bf16)(v.x - (float)hh[0]);
                hh[1] = (__bf16)v.y; ll[1] = (__bf16)(v.y - (float)hh[1]);
                hh[2] = (__bf16)v.z; ll[2] = (__bf16)(v.z - (float)hh[2]);
                hh[3] = (__bf16)v.w; ll[3] = (__bf16)(v.w - (float)hh[3]);
                *(bf16x4*)&sAh[r * 40 + hf * 16 + q * 4] = hh;
                *(bf16x4*)&sAl[r * 40 + hf * 16 + q * 4] = ll;
            }
        }
        {
            size_t gb = (size_t)(n0 + r) * 256 + kk + hf * 16;
            uint4 vh0 = *(const uint4*)(Bth + gb);
            uint4 vh1 = *(const uint4*)(Bth + gb + 8);
            uint4 vl0 = *(const uint4*)(Btl + gb);
            uint4 vl1 = *(const uint4*)(Btl + gb + 8);
            *(uint4*)&sBh[r * 40 + hf * 16]     = vh0;
            *(uint4*)&sBh[r * 40 + hf * 16 + 8] = vh1;
            *(uint4*)&sBl[r * 40 + hf * 16]     = vl0;
            *(uint4*)&sBl[r * 40 + hf * 16 + 8] = vl1;
        }
        __syncthreads();

        int m_base = wm + (lane & 15);
        int n_base = wn + (lane & 15);
        int koff = (lane >> 4) * 8;
        bf16x8 ah[4], al[4], bh[4], bl[4];
        #pragma unroll
        for (int mt = 0; mt < 4; mt++) {
            ah[mt] = *(const bf16x8*)&sAh[(m_base + mt * 16) * 40 + koff];
            al[mt] = *(const bf16x8*)&sAl[(m_base + mt * 16) * 40 + koff];
        }
        #pragma unroll
        for (int nt = 0; nt < 4; nt++) {
            bh[nt] = *(const bf16x8*)&sBh[(n_base + nt * 16) * 40 + koff];
            bl[nt] = *(const bf16x8*)&sBl[(n_base + nt * 16) * 40 + koff];
        }
        #pragma unroll
        for (int mt = 0; mt < 4; mt++)
            #pragma unroll
            for (int nt = 0; nt < 4; nt++) {
                acc[mt][nt] = __builtin_amdgcn_mfma_f32_16x16x32_bf16(ah[mt], bh[nt], acc[mt][nt], 0, 0, 0);
                acc[mt][nt] = __builtin_amdgcn_mfma_f32_16x16x32_bf16(al[mt], bh[nt], acc[mt][nt], 0, 0, 0);
                acc[mt][nt] = __builtin_amdgcn_mfma_f32_16x16x32_bf16(ah[mt], bl[nt], acc[mt][nt], 0, 0, 0);
            }
        __syncthreads();
    }

    #pragma unroll
    for (int mt = 0; mt < 4; mt++) {
        #pragma unroll
        for (int nt = 0; nt < 4; nt++) {
            int col = n0 + wn + nt * 16 + (lane & 15);
            #pragma unroll
            for (int rr = 0; rr < 4; rr++) {
                int row = row0 + wm + mt * 16 + (lane >> 4) * 4 + rr;
                if (row < nrows) {
                    float v = acc[mt][nt][rr] + bias[col];
                    if (do_relu) v = fmaxf(v, 0.f);
                    if (Cb) {
                        Cb[(size_t)row * 256 + col] = (__bf16)v;
                    } else {
                        if (residual) v += residual[(size_t)row * 256 + col];
                        C[(size_t)row * 256 + col] = v;
                    }
                }
            }
        }
    }
}

// ---- CSR build ----
__global__ void hist_kernel(const int* __restrict__ recv, int* __restrict__ counts) {
    int t = blockIdx.x * 256 + threadIdx.x;
    if (t < M_EDGES) atomicAdd(&counts[recv[t]], 1);
}

__global__ void scan_kernel(const int* __restrict__ counts, int* __restrict__ offsets) {
    __shared__ int part[256];
    int t = threadIdx.x;
    const int per = (N_NODES + 255) / 256;
    int start = t * per;
    int end = min(start + per, N_NODES);
    int s = 0;
    for (int i = start; i < end; i++) s += counts[i];
    part[t] = s;
    __syncthreads();
    if (t == 0) {
        int acc = 0;
        for (int i = 0; i < 256; i++) { int v = part[i]; part[i] = acc; acc += v; }
    }
    __syncthreads();
    int acc = part[t];
    for (int i = start; i < end; i++) { offsets[i] = acc; acc += counts[i]; }
    if (end == N_NODES && start < N_NODES) offsets[N_NODES] = acc;
}

__global__ void fill_kernel(const int* __restrict__ recv, const int* __restrict__ send,
                            const int* __restrict__ offsets,
                            int* __restrict__ cursor, int* __restrict__ ssorted) {
    int t = blockIdx.x * 256 + threadIdx.x;
    if (t < M_EDGES) {
        int r = recv[t];
        int pos = offsets[r] + atomicAdd(&cursor[r], 1);
        ssorted[pos] = send[t];
    }
}

// ---- edge logits, CSR order. 2 edges per wave-iteration (32 lanes x 16B per K row),
// 2-stage software pipeline: indices 2 pairs ahead, K rows 1 pair ahead.
__global__ __launch_bounds__(256) void qk_csr_kernel(
    const int* __restrict__ offsets, const int* __restrict__ ssorted,
    const float* __restrict__ Q, const unsigned short* __restrict__ Kb,
    float* __restrict__ qks, unsigned* __restrict__ gmax) {
    __shared__ float swmax[4];
    int wave = threadIdx.x >> 6, lane = threadIdx.x & 63;
    int e_slot = lane >> 5;        // which edge of the pair
    int sl = lane & 31;            // 16B chunk within row
    int n = blockIdx.x * 4 + wave;
    float wmax = -INFINITY;
    if (n < N_NODES) {
        int off = offsets[n], deg = offsets[n + 1] - off;
        float4 qa = *(const float4*)(Q + (size_t)n * 256 + sl * 8);
        float4 qb = *(const float4*)(Q + (size_t)n * 256 + sl * 8 + 4);
        if (deg > 0) {
            int npairs = (deg + 1) >> 1;
            int s_cur = (e_slot < deg) ? ssorted[off + e_slot] : 0;
            int s_nxt = (2 + e_slot < deg) ? ssorted[off + 2 + e_slot] : 0;
            uint4 kv_cur = *(const uint4*)(Kb + (size_t)s_cur * 256 + sl * 8);
            for (int p = 0; p < npairs; p++) {
                int jf = p * 2 + 4 + e_slot;
                int s2 = (jf < deg) ? ssorted[off + jf] : 0;
                uint4 kv_nxt = *(const uint4*)(Kb + (size_t)s_nxt * 256 + sl * 8);
                int jc = p * 2 + e_slot;
                float d = qa.x * bflo(kv_cur.x) + qa.y * bfhi(kv_cur.x)
                        + qa.z * bflo(kv_cur.y) + qa.w * bfhi(kv_cur.y)
                        + qb.x * bflo(kv_cur.z) + qb.y * bfhi(kv_cur.z)
                        + qb.z * bflo(kv_cur.w) + qb.w * bfhi(kv_cur.w);
                d += __shfl_xor(d, 1);
                d += __shfl_xor(d, 2);   // full head dot in all 4 lanes of the quad
                if (jc < deg) {
                    wmax = fmaxf(wmax, d);
                    if ((sl & 3) == 0) qks[(size_t)(off + jc) * 8 + (sl >> 2)] = d;
                }
                kv_cur = kv_nxt; s_nxt = s2;
            }
        }
    }
    wmax = fmaxf(wmax, __shfl_xor(wmax, 4));
    wmax = fmaxf(wmax, __shfl_xor(wmax, 8));
    wmax = fmaxf(wmax, __shfl_xor(wmax, 16));
    wmax = fmaxf(wmax, __shfl_xor(wmax, 32));
    if (lane == 0) swmax[wave] = wmax;
    __syncthreads();
    if (threadIdx.x == 0) {
        float m = fmaxf(fmaxf(swmax[0], swmax[1]), fmaxf(swmax[2], swmax[3]));
        if (m > -INFINITY) atomicMax(gmax, enc_ord(m));
    }
}

// ---- node aggregation: 4 waves per node, each wave owns a strided quarter of the
// edges; lane covers 4 contiguous V columns (uint2 = 4 bf16). 2-stage pipeline.
// Cross-wave LDS reduction at the end.
__global__ __launch_bounds__(256) void node_agg_kernel(
    const int* __restrict__ offsets, const int* __restrict__ ssorted,
    const float* __restrict__ qks, const unsigned short* __restrict__ Vb,
    const unsigned* __restrict__ gmax, float* __restrict__ msg) {
    __shared__ float s_part[4][256];
    __shared__ float s_sums[4][8];
    int n = blockIdx.x;
    int j = threadIdx.x >> 6;      // wave slot: edges j, j+4, j+8, ...
    int l = threadIdx.x & 63;      // columns l*4 .. l*4+3
    int h = l >> 3;                // head of these columns
    int off = offsets[n];
    int deg = offsets[n + 1] - off;
    float scale = 3.0f / dec_ord(*gmax);
    float sum = 0.f;
    float a0 = 0.f, a1 = 0.f, a2 = 0.f, a3 = 0.f;
    if (j < deg) {
        int s_cur = ssorted[off + j];
        int s_nxt = (j + 4 < deg) ? ssorted[off + j + 4] : 0;
        float qv_cur = qks[(size_t)(off + j) * 8 + h];
        uint2 v_cur = *(const uint2*)(Vb + (size_t)s_cur * 256 + l * 4);
        for (int i = j; i < deg; i += 4) {
            int i2 = i + 8;
            int s2 = (i2 < deg) ? ssorted[off + i2] : 0;
            float qv_nxt = (i + 4 < deg) ? qks[(size_t)(off + i + 4) * 8 + h] : 0.f;
            uint2 v_nxt = *(const uint2*)(Vb + (size_t)s_nxt * 256 + l * 4);
            float a = __expf(qv_cur * scale);
            sum += a;
            a0 += a * bflo(v_cur.x); a1 += a * bfhi(v_cur.x);
            a2 += a * bflo(v_cur.y); a3 += a * bfhi(v_cur.y);
            v_cur = v_nxt; s_nxt = s2; qv_cur = qv_nxt;
        }
    }
    *(float4*)&s_part[j][l * 4] = make_float4(a0, a1, a2, a3);
    if ((l & 7) == 0) s_sums[j][h] = sum;
    __syncthreads();
    int c = threadIdx.x;
    int ch = c >> 5;
    float tot = s_sums[0][ch] + s_sums[1][ch] + s_sums[2][ch] + s_sums[3][ch];
    float acc = s_part[0][c] + s_part[1][c] + s_part[2][c] + s_part[3][c];
    float inv = (deg > 0) ? 1.0f / (tot * 5.65685424949238f) : 0.f;  // sqrt(32)
    msg[(size_t)n * 256 + c] = fmaxf(acc * inv, 0.f);
}

extern "C" void kernel_launch(void* const* d_in, const int* in_sizes, int n_in,
                              void* d_out, int out_size, void* d_ws, size_t ws_size,
                              hipStream_t stream) {
    const float* x    = (const float*)d_in[0];
    const int*   edge = (const int*)d_in[1];
    const int*   recv = edge;
    const int*   send = edge + M_EDGES;
    const float* Wk   = (const float*)d_in[2];
    const float* bk   = (const float*)d_in[3];
    const float* Wq   = (const float*)d_in[4];
    const float* bq   = (const float*)d_in[5];
    const float* Wv   = (const float*)d_in[6];
    const float* bv   = (const float*)d_in[7];
    const float* Wagg = (const float*)d_in[8];
    const float* bagg = (const float*)d_in[9];
    const float* Wff  = (const float*)d_in[10];
    const float* bff  = (const float*)d_in[11];
    float* out = (float*)d_out;

    float*  Qbuf  = (float*)d_ws;
    float*  msg   = Qbuf + (size_t)N_NODES * 256;
    float*  qks   = msg + (size_t)N_NODES * 256;
    __bf16* Kbf   = (__bf16*)(qks + (size_t)M_EDGES * 8);
    __bf16* Vbf   = Kbf + (size_t)N_NODES * 256;
    int* counts   = (int*)(Vbf + (size_t)N_NODES * 256);
    int* cursor   = counts + N_NODES;
    int* offsets  = cursor + N_NODES;
    int* ssorted  = offsets + N_NODES + 1;
    unsigned* gmax = (unsigned*)(ssorted + M_EDGES);
    __bf16* wt    = (__bf16*)(gmax + 1);
    __bf16* WkH = wt;              __bf16* WkL = wt + 65536;
    __bf16* WqH = wt + 2 * 65536;  __bf16* WqL = wt + 3 * 65536;
    __bf16* WvH = wt + 4 * 65536;  __bf16* WvL = wt + 5 * 65536;
    __bf16* WaH = wt + 6 * 65536;  __bf16* WaL = wt + 7 * 65536;
    __bf16* WfH = wt + 8 * 65536;  __bf16* WfL = wt + 9 * 65536;
    float* hidden = Qbuf;  // reuse: Q dead after qk_csr_kernel

    dim3 blk(256);
    dim3 gemm_grid((N_NODES + 127) / 128, 2);
    dim3 edge_grid((M_EDGES + 255) / 256);

    hipLaunchKernelGGL(init_kernel, dim3((N_NODES + 255) / 256), blk, 0, stream,
                       counts, cursor, gmax);
    hipLaunchKernelGGL(wsplit_kernel, dim3(256), blk, 0, stream, Wk,   WkH, WkL);
    hipLaunchKernelGGL(wsplit_kernel, dim3(256), blk, 0, stream, Wq,   WqH, WqL);
    hipLaunchKernelGGL(wsplit_kernel, dim3(256), blk, 0, stream, Wv,   WvH, WvL);
    hipLaunchKernelGGL(wsplit_kernel, dim3(256), blk, 0, stream, Wagg, WaH, WaL);
    hipLaunchKernelGGL(wsplit_kernel, dim3(256), blk, 0, stream, Wff,  WfH, WfL);
    // projections (MFMA); K,V emitted as bf16, Q fp32
    hipLaunchKernelGGL(gemm_mfma, gemm_grid, blk, 0, stream, x, WkH, WkL, bk, nullptr,
                       (float*)nullptr, Kbf, N_NODES, 0);
    hipLaunchKernelGGL(gemm_mfma, gemm_grid, blk, 0, stream, x, WqH, WqL, bq, nullptr,
                       Qbuf, (__bf16*)nullptr, N_NODES, 0);
    hipLaunchKernelGGL(gemm_mfma, gemm_grid, blk, 0, stream, x, WvH, WvL, bv, nullptr,
                       (float*)nullptr, Vbf, N_NODES, 0);
    // CSR build
    hipLaunchKernelGGL(hist_kernel, edge_grid, blk, 0, stream, recv, counts);
    hipLaunchKernelGGL(scan_kernel, dim3(1), blk, 0, stream, counts, offsets);
    hipLaunchKernelGGL(fill_kernel, edge_grid, blk, 0, stream, recv, send, offsets, cursor, ssorted);
    // edge logits + global max
    hipLaunchKernelGGL(qk_csr_kernel, dim3((N_NODES + 3) / 4), blk, 0, stream,
                       offsets, ssorted, Qbuf, (const unsigned short*)Kbf, qks, gmax);
    // segment softmax + aggregate
    hipLaunchKernelGGL(node_agg_kernel, dim3(N_NODES), blk, 0, stream,
                       offsets, ssorted, qks, (const unsigned short*)Vbf, gmax, msg);
    // output MLP (MFMA)
    hipLaunchKernelGGL(gemm_mfma, gemm_grid, blk, 0, stream, msg, WaH, WaL, bagg, nullptr,
                       hidden, (__bf16*)nullptr, N_NODES, 1);
    hipLaunchKernelGGL(gemm_mfma, gemm_grid, blk, 0, stream, hidden, WfH, WfL, bff, x,
                       out, (__bf16*)nullptr, N_NODES, 1);
}

// Round 6
// 880.241 us; speedup vs baseline: 1.7393x; 1.0058x over previous
//
#include <hip/hip_runtime.h>

#define N_NODES 50000
#define M_EDGES 800000

typedef __bf16 bf16x8 __attribute__((ext_vector_type(8)));
typedef __bf16 bf16x4 __attribute__((ext_vector_type(4)));
typedef float  f32x4  __attribute__((ext_vector_type(4)));

static __device__ __forceinline__ unsigned enc_ord(float f) {
    unsigned b = __float_as_uint(f);
    return (b & 0x80000000u) ? ~b : (b | 0x80000000u);
}
static __device__ __forceinline__ float dec_ord(unsigned u) {
    unsigned b = (u & 0x80000000u) ? (u ^ 0x80000000u) : ~u;
    return __uint_as_float(b);
}
// bf16 pair packed in a uint: lo = bits[15:0], hi = bits[31:16]
static __device__ __forceinline__ float bflo(unsigned u) { return __uint_as_float(u << 16); }
static __device__ __forceinline__ float bfhi(unsigned u) { return __uint_as_float(u & 0xffff0000u); }

__global__ void init_kernel(int* counts, int* cursor, unsigned* gmax) {
    int t = blockIdx.x * blockDim.x + threadIdx.x;
    if (t < N_NODES) { counts[t] = 0; cursor[t] = 0; }
    if (t == 0) *gmax = 0u;
}

__global__ void wsplit_kernel(const float* __restrict__ W,
                              __bf16* __restrict__ th, __bf16* __restrict__ tl) {
    int t = blockIdx.x * 256 + threadIdx.x;
    int n = t >> 8, k = t & 255;
    float v = W[(size_t)k * 256 + n];
    __bf16 h = (__bf16)v;
    th[t] = h;
    tl[t] = (__bf16)(v - (float)h);
}

// ---- split-bf16 MFMA GEMM. Output: fp32 C (with optional relu/residual) OR bf16 Cb.
__global__ __launch_bounds__(256) void gemm_mfma(
    const float* __restrict__ A,
    const __bf16* __restrict__ Bth, const __bf16* __restrict__ Btl,
    const float* __restrict__ bias, const float* __restrict__ residual,
    float* __restrict__ C, __bf16* __restrict__ Cb, int nrows, int do_relu) {
    __shared__ __attribute__((aligned(16))) __bf16 sAh[128 * 40];
    __shared__ __attribute__((aligned(16))) __bf16 sAl[128 * 40];
    __shared__ __attribute__((aligned(16))) __bf16 sBh[128 * 40];
    __shared__ __attribute__((aligned(16))) __bf16 sBl[128 * 40];

    int row0 = blockIdx.x * 128;
    int n0   = blockIdx.y * 128;
    int tid  = threadIdx.x;
    int lane = tid & 63, wave = tid >> 6;
    int wm = (wave >> 1) * 64, wn = (wave & 1) * 64;

    f32x4 acc[4][4];
    #pragma unroll
    for (int i = 0; i < 4; i++)
        #pragma unroll
        for (int j = 0; j < 4; j++) acc[i][j] = (f32x4)(0.f);

    int r  = tid >> 1;
    int hf = tid & 1;

    for (int kk = 0; kk < 256; kk += 32) {
        {
            const float* ap = A + (size_t)(row0 + r) * 256 + kk + hf * 16;
            bool valid = (row0 + r) < nrows;
            #pragma unroll
            for (int q = 0; q < 4; q++) {
                float4 v = valid ? *(const float4*)(ap + q * 4)
                                 : make_float4(0.f, 0.f, 0.f, 0.f);
                bf16x4 hh, ll;
                hh[0] = (__bf16)v.x; ll[0] = (__bf16)(v.x - (float)hh[0]);
                hh[1] = (__bf16)v.y; ll[1] = (__bf16)(v.y - (float)hh[1]);
                hh[2] = (__bf16)v.z; ll[2] = (__bf16)(v.z - (float)hh[2]);
                hh[3] = (__bf16)v.w; ll[3] = (__bf16)(v.w - (float)hh[3]);
                *(bf16x4*)&sAh[r * 40 + hf * 16 + q * 4] = hh;
                *(bf16x4*)&sAl[r * 40 + hf * 16 + q * 4] = ll;
            }
        }
        {
            size_t gb = (size_t)(n0 + r) * 256 + kk + hf * 16;
            uint4 vh0 = *(const uint4*)(Bth + gb);
            uint4 vh1 = *(const uint4*)(Bth + gb + 8);
            uint4 vl0 = *(const uint4*)(Btl + gb);
            uint4 vl1 = *(const uint4*)(Btl + gb + 8);
            *(uint4*)&sBh[r * 40 + hf * 16]     = vh0;
            *(uint4*)&sBh[r * 40 + hf * 16 + 8] = vh1;
            *(uint4*)&sBl[r * 40 + hf * 16]     = vl0;
            *(uint4*)&sBl[r * 40 + hf * 16 + 8] = vl1;
        }
        __syncthreads();

        int m_base = wm + (lane & 15);
        int n_base = wn + (lane & 15);
        int koff = (lane >> 4) * 8;
        bf16x8 ah[4], al[4], bh[4], bl[4];
        #pragma unroll
        for (int mt = 0; mt < 4; mt++) {
            ah[mt] = *(const bf16x8*)&sAh[(m_base + mt * 16) * 40 + koff];
            al[mt] = *(const bf16x8*)&sAl[(m_base + mt * 16) * 40 + koff];
        }
        #pragma unroll
        for (int nt = 0; nt < 4; nt++) {
            bh[nt] = *(const bf16x8*)&sBh[(n_base + nt * 16) * 40 + koff];
            bl[nt] = *(const bf16x8*)&sBl[(n_base + nt * 16) * 40 + koff];
        }
        #pragma unroll
        for (int mt = 0; mt < 4; mt++)
            #pragma unroll
            for (int nt = 0; nt < 4; nt++) {
                acc[mt][nt] = __builtin_amdgcn_mfma_f32_16x16x32_bf16(ah[mt], bh[nt], acc[mt][nt], 0, 0, 0);
                acc[mt][nt] = __builtin_amdgcn_mfma_f32_16x16x32_bf16(al[mt], bh[nt], acc[mt][nt], 0, 0, 0);
                acc[mt][nt] = __builtin_amdgcn_mfma_f32_16x16x32_bf16(ah[mt], bl[nt], acc[mt][nt], 0, 0, 0);
            }
        __syncthreads();
    }

    #pragma unroll
    for (int mt = 0; mt < 4; mt++) {
        #pragma unroll
        for (int nt = 0; nt < 4; nt++) {
            int col = n0 + wn + nt * 16 + (lane & 15);
            #pragma unroll
            for (int rr = 0; rr < 4; rr++) {
                int row = row0 + wm + mt * 16 + (lane >> 4) * 4 + rr;
                if (row < nrows) {
                    float v = acc[mt][nt][rr] + bias[col];
                    if (do_relu) v = fmaxf(v, 0.f);
                    if (Cb) {
                        Cb[(size_t)row * 256 + col] = (__bf16)v;
                    } else {
                        if (residual) v += residual[(size_t)row * 256 + col];
                        C[(size_t)row * 256 + col] = v;
                    }
                }
            }
        }
    }
}

// ---- CSR build ----
__global__ void hist_kernel(const int* __restrict__ recv, int* __restrict__ counts) {
    int t = blockIdx.x * 256 + threadIdx.x;
    if (t < M_EDGES) atomicAdd(&counts[recv[t]], 1);
}

__global__ void scan_kernel(const int* __restrict__ counts, int* __restrict__ offsets) {
    __shared__ int part[256];
    int t = threadIdx.x;
    const int per = (N_NODES + 255) / 256;
    int start = t * per;
    int end = min(start + per, N_NODES);
    int s = 0;
    for (int i = start; i < end; i++) s += counts[i];
    part[t] = s;
    __syncthreads();
    if (t == 0) {
        int acc = 0;
        for (int i = 0; i < 256; i++) { int v = part[i]; part[i] = acc; acc += v; }
    }
    __syncthreads();
    int acc = part[t];
    for (int i = start; i < end; i++) { offsets[i] = acc; acc += counts[i]; }
    if (end == N_NODES && start < N_NODES) offsets[N_NODES] = acc;
}

__global__ void fill_kernel(const int* __restrict__ recv, const int* __restrict__ send,
                            const int* __restrict__ offsets,
                            int* __restrict__ cursor, int* __restrict__ ssorted) {
    int t = blockIdx.x * 256 + threadIdx.x;
    if (t < M_EDGES) {
        int r = recv[t];
        int pos = offsets[r] + atomicAdd(&cursor[r], 1);
        ssorted[pos] = send[t];
    }
}

// ---- edge logits, CSR order. One wave per node. Indices batch-staged in a register
// (32 per coalesced load, fetched via __shfl -> no index load in the steady chain).
// K rows ring-buffered 3 pairs deep: 6 edge-rows (3 KB) in flight per wave.
__global__ __launch_bounds__(256) void qk_csr_kernel(
    const int* __restrict__ offsets, const int* __restrict__ ssorted,
    const float* __restrict__ Q, const unsigned short* __restrict__ Kb,
    float* __restrict__ qks, unsigned* __restrict__ gmax) {
    __shared__ float swmax[4];
    int wave = threadIdx.x >> 6, lane = threadIdx.x & 63;
    int e_slot = lane >> 5;        // which edge of the pair
    int sl = lane & 31;            // 16B chunk within row
    int n = blockIdx.x * 4 + wave;
    float wmax = -INFINITY;
    if (n < N_NODES) {
        int off = offsets[n], deg = offsets[n + 1] - off;
        float4 qa = *(const float4*)(Q + (size_t)n * 256 + sl * 8);
        float4 qb = *(const float4*)(Q + (size_t)n * 256 + sl * 8 + 4);
        for (int b = 0; b < deg; b += 32) {
            int bn = min(32, deg - b);
            int idx = ssorted[off + b + min(sl, bn - 1)];   // coalesced, dup halves
            int npairs = (bn + 1) >> 1;
            #define ROWLOAD(p) (*(const uint4*)(Kb + \
                (size_t)__shfl(idx, min(2 * (p) + e_slot, bn - 1)) * 256 + sl * 8))
            uint4 kv0 = ROWLOAD(0);
            uint4 kv1 = ROWLOAD(1);
            uint4 kv2 = ROWLOAD(2);
            for (int p = 0; p < npairs; p++) {
                uint4 kc = kv0;
                kv0 = kv1; kv1 = kv2;
                kv2 = ROWLOAD(p + 3);
                float d = qa.x * bflo(kc.x) + qa.y * bfhi(kc.x)
                        + qa.z * bflo(kc.y) + qa.w * bfhi(kc.y)
                        + qb.x * bflo(kc.z) + qb.y * bfhi(kc.z)
                        + qb.z * bflo(kc.w) + qb.w * bfhi(kc.w);
                d += __shfl_xor(d, 1);
                d += __shfl_xor(d, 2);   // full head dot in all 4 lanes of the quad
                int jc = p * 2 + e_slot;
                if (jc < bn) {
                    wmax = fmaxf(wmax, d);
                    if ((sl & 3) == 0) qks[(size_t)(off + b + jc) * 8 + (sl >> 2)] = d;
                }
            }
            #undef ROWLOAD
        }
    }
    wmax = fmaxf(wmax, __shfl_xor(wmax, 4));
    wmax = fmaxf(wmax, __shfl_xor(wmax, 8));
    wmax = fmaxf(wmax, __shfl_xor(wmax, 16));
    wmax = fmaxf(wmax, __shfl_xor(wmax, 32));
    if (lane == 0) swmax[wave] = wmax;
    __syncthreads();
    if (threadIdx.x == 0) {
        float m = fmaxf(fmaxf(swmax[0], swmax[1]), fmaxf(swmax[2], swmax[3]));
        if (m > -INFINITY) atomicMax(gmax, enc_ord(m));
    }
}

// ---- node aggregation: 4 waves per node, wave j owns edges j, j+4, ...
// Indices staged 16-at-a-time via lane-load + __shfl; V rows + qks 2-deep pipeline.
__global__ __launch_bounds__(256) void node_agg_kernel(
    const int* __restrict__ offsets, const int* __restrict__ ssorted,
    const float* __restrict__ qks, const unsigned short* __restrict__ Vb,
    const unsigned* __restrict__ gmax, float* __restrict__ msg) {
    __shared__ float s_part[4][256];
    __shared__ float s_sums[4][8];
    int n = blockIdx.x;
    int j = threadIdx.x >> 6;      // wave slot
    int l = threadIdx.x & 63;      // columns l*4 .. l*4+3
    int h = l >> 3;                // head of these columns
    int off = offsets[n];
    int deg = offsets[n + 1] - off;
    float scale = 3.0f / dec_ord(*gmax);
    float sum = 0.f;
    float a0 = 0.f, a1 = 0.f, a2 = 0.f, a3 = 0.f;
    if (j < deg) {
        for (int tb = 0; j + 4 * tb < deg; tb += 16) {
            // stage up to 16 indices for this wave: t-th edge at CSR pos j+4*(tb+t)
            int tpos = j + 4 * (tb + (l & 15));
            int idx = ssorted[off + min(tpos, deg - 1)];
            int tn = min(16, ((deg - 1 - j) >> 2) + 1 - tb);   // valid t count this batch
            #define VROW(t) (*(const uint2*)(Vb + \
                (size_t)__shfl(idx, min(t, tn - 1)) * 256 + l * 4))
            #define QV(t) qks[(size_t)(off + min(j + 4 * (tb + (t)), deg - 1)) * 8 + h]
            uint2 v0 = VROW(0);
            uint2 v1 = VROW(1);
            float q0 = QV(0);
            float q1 = QV(1);
            for (int t = 0; t < tn; t++) {
                uint2 vc = v0; v0 = v1; v1 = VROW(t + 2);
                float qc = q0; q0 = q1; q1 = QV(t + 2);
                float a = __expf(qc * scale);
                sum += a;
                a0 += a * bflo(vc.x); a1 += a * bfhi(vc.x);
                a2 += a * bflo(vc.y); a3 += a * bfhi(vc.y);
            }
            #undef VROW
            #undef QV
        }
    }
    *(float4*)&s_part[j][l * 4] = make_float4(a0, a1, a2, a3);
    if ((l & 7) == 0) s_sums[j][h] = sum;
    __syncthreads();
    int c = threadIdx.x;
    int ch = c >> 5;
    float tot = s_sums[0][ch] + s_sums[1][ch] + s_sums[2][ch] + s_sums[3][ch];
    float acc = s_part[0][c] + s_part[1][c] + s_part[2][c] + s_part[3][c];
    float inv = (deg > 0) ? 1.0f / (tot * 5.65685424949238f) : 0.f;  // sqrt(32)
    msg[(size_t)n * 256 + c] = fmaxf(acc * inv, 0.f);
}

extern "C" void kernel_launch(void* const* d_in, const int* in_sizes, int n_in,
                              void* d_out, int out_size, void* d_ws, size_t ws_size,
                              hipStream_t stream) {
    const float* x    = (const float*)d_in[0];
    const int*   edge = (const int*)d_in[1];
    const int*   recv = edge;
    const int*   send = edge + M_EDGES;
    const float* Wk   = (const float*)d_in[2];
    const float* bk   = (const float*)d_in[3];
    const float* Wq   = (const float*)d_in[4];
    const float* bq   = (const float*)d_in[5];
    const float* Wv   = (const float*)d_in[6];
    const float* bv   = (const float*)d_in[7];
    const float* Wagg = (const float*)d_in[8];
    const float* bagg = (const float*)d_in[9];
    const float* Wff  = (const float*)d_in[10];
    const float* bff  = (const float*)d_in[11];
    float* out = (float*)d_out;

    float*  Qbuf  = (float*)d_ws;
    float*  msg   = Qbuf + (size_t)N_NODES * 256;
    float*  qks   = msg + (size_t)N_NODES * 256;
    __bf16* Kbf   = (__bf16*)(qks + (size_t)M_EDGES * 8);
    __bf16* Vbf   = Kbf + (size_t)N_NODES * 256;
    int* counts   = (int*)(Vbf + (size_t)N_NODES * 256);
    int* cursor   = counts + N_NODES;
    int* offsets  = cursor + N_NODES;
    int* ssorted  = offsets + N_NODES + 1;
    unsigned* gmax = (unsigned*)(ssorted + M_EDGES);
    __bf16* wt    = (__bf16*)(gmax + 1);
    __bf16* WkH = wt;              __bf16* WkL = wt + 65536;
    __bf16* WqH = wt + 2 * 65536;  __bf16* WqL = wt + 3 * 65536;
    __bf16* WvH = wt + 4 * 65536;  __bf16* WvL = wt + 5 * 65536;
    __bf16* WaH = wt + 6 * 65536;  __bf16* WaL = wt + 7 * 65536;
    __bf16* WfH = wt + 8 * 65536;  __bf16* WfL = wt + 9 * 65536;
    float* hidden = Qbuf;  // reuse: Q dead after qk_csr_kernel

    dim3 blk(256);
    dim3 gemm_grid((N_NODES + 127) / 128, 2);
    dim3 edge_grid((M_EDGES + 255) / 256);

    hipLaunchKernelGGL(init_kernel, dim3((N_NODES + 255) / 256), blk, 0, stream,
                       counts, cursor, gmax);
    hipLaunchKernelGGL(wsplit_kernel, dim3(256), blk, 0, stream, Wk,   WkH, WkL);
    hipLaunchKernelGGL(wsplit_kernel, dim3(256), blk, 0, stream, Wq,   WqH, WqL);
    hipLaunchKernelGGL(wsplit_kernel, dim3(256), blk, 0, stream, Wv,   WvH, WvL);
    hipLaunchKernelGGL(wsplit_kernel, dim3(256), blk, 0, stream, Wagg, WaH, WaL);
    hipLaunchKernelGGL(wsplit_kernel, dim3(256), blk, 0, stream, Wff,  WfH, WfL);
    // projections (MFMA); K,V emitted as bf16, Q fp32
    hipLaunchKernelGGL(gemm_mfma, gemm_grid, blk, 0, stream, x, WkH, WkL, bk, nullptr,
                       (float*)nullptr, Kbf, N_NODES, 0);
    hipLaunchKernelGGL(gemm_mfma, gemm_grid, blk, 0, stream, x, WqH, WqL, bq, nullptr,
                       Qbuf, (__bf16*)nullptr, N_NODES, 0);
    hipLaunchKernelGGL(gemm_mfma, gemm_grid, blk, 0, stream, x, WvH, WvL, bv, nullptr,
                       (float*)nullptr, Vbf, N_NODES, 0);
    // CSR build
    hipLaunchKernelGGL(hist_kernel, edge_grid, blk, 0, stream, recv, counts);
    hipLaunchKernelGGL(scan_kernel, dim3(1), blk, 0, stream, counts, offsets);
    hipLaunchKernelGGL(fill_kernel, edge_grid, blk, 0, stream, recv, send, offsets, cursor, ssorted);
    // edge logits + global max
    hipLaunchKernelGGL(qk_csr_kernel, dim3((N_NODES + 3) / 4), blk, 0, stream,
                       offsets, ssorted, Qbuf, (const unsigned short*)Kbf, qks, gmax);
    // segment softmax + aggregate
    hipLaunchKernelGGL(node_agg_kernel, dim3(N_NODES), blk, 0, stream,
                       offsets, ssorted, qks, (const unsigned short*)Vbf, gmax, msg);
    // output MLP (MFMA)
    hipLaunchKernelGGL(gemm_mfma, gemm_grid, blk, 0, stream, msg, WaH, WaL, bagg, nullptr,
                       hidden, (__bf16*)nullptr, N_NODES, 1);
    hipLaunchKernelGGL(gemm_mfma, gemm_grid, blk, 0, stream, hidden, WfH, WfL, bff, x,
                       out, (__bf16*)nullptr, N_NODES, 1);
}

// Round 7
// 870.048 us; speedup vs baseline: 1.7597x; 1.0117x over previous
//
#include <hip/hip_runtime.h>

#define N_NODES 50000
#define M_EDGES 800000

typedef __bf16 bf16x8 __attribute__((ext_vector_type(8)));
typedef __bf16 bf16x4 __attribute__((ext_vector_type(4)));
typedef float  f32x4  __attribute__((ext_vector_type(4)));

static __device__ __forceinline__ unsigned enc_ord(float f) {
    unsigned b = __float_as_uint(f);
    return (b & 0x80000000u) ? ~b : (b | 0x80000000u);
}
static __device__ __forceinline__ float dec_ord(unsigned u) {
    unsigned b = (u & 0x80000000u) ? (u ^ 0x80000000u) : ~u;
    return __uint_as_float(b);
}
// bf16 pair packed in a uint: lo = bits[15:0], hi = bits[31:16]
static __device__ __forceinline__ float bflo(unsigned u) { return __uint_as_float(u << 16); }
static __device__ __forceinline__ float bfhi(unsigned u) { return __uint_as_float(u & 0xffff0000u); }

__global__ void init_kernel(int* counts, int* cursor, unsigned* gmax) {
    int t = blockIdx.x * blockDim.x + threadIdx.x;
    if (t < N_NODES) { counts[t] = 0; cursor[t] = 0; }
    if (t == 0) *gmax = 0u;
}

__global__ void wsplit_kernel(const float* __restrict__ W,
                              __bf16* __restrict__ th, __bf16* __restrict__ tl) {
    int t = blockIdx.x * 256 + threadIdx.x;
    int n = t >> 8, k = t & 255;
    float v = W[(size_t)k * 256 + n];
    __bf16 h = (__bf16)v;
    th[t] = h;
    tl[t] = (__bf16)(v - (float)h);
}

// ---- split-bf16 MFMA GEMM. Output: fp32 C (with optional relu/residual) OR bf16 Cb.
__global__ __launch_bounds__(256) void gemm_mfma(
    const float* __restrict__ A,
    const __bf16* __restrict__ Bth, const __bf16* __restrict__ Btl,
    const float* __restrict__ bias, const float* __restrict__ residual,
    float* __restrict__ C, __bf16* __restrict__ Cb, int nrows, int do_relu) {
    __shared__ __attribute__((aligned(16))) __bf16 sAh[128 * 40];
    __shared__ __attribute__((aligned(16))) __bf16 sAl[128 * 40];
    __shared__ __attribute__((aligned(16))) __bf16 sBh[128 * 40];
    __shared__ __attribute__((aligned(16))) __bf16 sBl[128 * 40];

    int row0 = blockIdx.x * 128;
    int n0   = blockIdx.y * 128;
    int tid  = threadIdx.x;
    int lane = tid & 63, wave = tid >> 6;
    int wm = (wave >> 1) * 64, wn = (wave & 1) * 64;

    f32x4 acc[4][4];
    #pragma unroll
    for (int i = 0; i < 4; i++)
        #pragma unroll
        for (int j = 0; j < 4; j++) acc[i][j] = (f32x4)(0.f);

    int r  = tid >> 1;
    int hf = tid & 1;

    for (int kk = 0; kk < 256; kk += 32) {
        {
            const float* ap = A + (size_t)(row0 + r) * 256 + kk + hf * 16;
            bool valid = (row0 + r) < nrows;
            #pragma unroll
            for (int q = 0; q < 4; q++) {
                float4 v = valid ? *(const float4*)(ap + q * 4)
                                 : make_float4(0.f, 0.f, 0.f, 0.f);
                bf16x4 hh, ll;
                hh[0] = (__bf16)v.x; ll[0] = (__bf16)(v.x - (float)hh[0]);
                hh[1] = (__bf16)v.y; ll[1] = (__bf16)(v.y - (float)hh[1]);
                hh[2] = (__bf16)v.z; ll[2] = (__bf16)(v.z - (float)hh[2]);
                hh[3] = (__bf16)v.w; ll[3] = (__bf16)(v.w - (float)hh[3]);
                *(bf16x4*)&sAh[r * 40 + hf * 16 + q * 4] = hh;
                *(bf16x4*)&sAl[r * 40 + hf * 16 + q * 4] = ll;
            }
        }
        {
            size_t gb = (size_t)(n0 + r) * 256 + kk + hf * 16;
            uint4 vh0 = *(const uint4*)(Bth + gb);
            uint4 vh1 = *(const uint4*)(Bth + gb + 8);
            uint4 vl0 = *(const uint4*)(Btl + gb);
            uint4 vl1 = *(const uint4*)(Btl + gb + 8);
            *(uint4*)&sBh[r * 40 + hf * 16]     = vh0;
            *(uint4*)&sBh[r * 40 + hf * 16 + 8] = vh1;
            *(uint4*)&sBl[r * 40 + hf * 16]     = vl0;
            *(uint4*)&sBl[r * 40 + hf * 16 + 8] = vl1;
        }
        __syncthreads();

        int m_base = wm + (lane & 15);
        int n_base = wn + (lane & 15);
        int koff = (lane >> 4) * 8;
        bf16x8 ah[4], al[4], bh[4], bl[4];
        #pragma unroll
        for (int mt = 0; mt < 4; mt++) {
            ah[mt] = *(const bf16x8*)&sAh[(m_base + mt * 16) * 40 + koff];
            al[mt] = *(const bf16x8*)&sAl[(m_base + mt * 16) * 40 + koff];
        }
        #pragma unroll
        for (int nt = 0; nt < 4; nt++) {
            bh[nt] = *(const bf16x8*)&sBh[(n_base + nt * 16) * 40 + koff];
            bl[nt] = *(const bf16x8*)&sBl[(n_base + nt * 16) * 40 + koff];
        }
        #pragma unroll
        for (int mt = 0; mt < 4; mt++)
            #pragma unroll
            for (int nt = 0; nt < 4; nt++) {
                acc[mt][nt] = __builtin_amdgcn_mfma_f32_16x16x32_bf16(ah[mt], bh[nt], acc[mt][nt], 0, 0, 0);
                acc[mt][nt] = __builtin_amdgcn_mfma_f32_16x16x32_bf16(al[mt], bh[nt], acc[mt][nt], 0, 0, 0);
                acc[mt][nt] = __builtin_amdgcn_mfma_f32_16x16x32_bf16(ah[mt], bl[nt], acc[mt][nt], 0, 0, 0);
            }
        __syncthreads();
    }

    #pragma unroll
    for (int mt = 0; mt < 4; mt++) {
        #pragma unroll
        for (int nt = 0; nt < 4; nt++) {
            int col = n0 + wn + nt * 16 + (lane & 15);
            #pragma unroll
            for (int rr = 0; rr < 4; rr++) {
                int row = row0 + wm + mt * 16 + (lane >> 4) * 4 + rr;
                if (row < nrows) {
                    float v = acc[mt][nt][rr] + bias[col];
                    if (do_relu) v = fmaxf(v, 0.f);
                    if (Cb) {
                        Cb[(size_t)row * 256 + col] = (__bf16)v;
                    } else {
                        if (residual) v += residual[(size_t)row * 256 + col];
                        C[(size_t)row * 256 + col] = v;
                    }
                }
            }
        }
    }
}

// ---- CSR build ----
__global__ void hist_kernel(const int* __restrict__ recv, int* __restrict__ counts) {
    int t = blockIdx.x * 256 + threadIdx.x;
    if (t < M_EDGES) atomicAdd(&counts[recv[t]], 1);
}

__global__ void scan_kernel(const int* __restrict__ counts, int* __restrict__ offsets) {
    __shared__ int part[256];
    int t = threadIdx.x;
    const int per = (N_NODES + 255) / 256;
    int start = t * per;
    int end = min(start + per, N_NODES);
    int s = 0;
    for (int i = start; i < end; i++) s += counts[i];
    part[t] = s;
    __syncthreads();
    if (t == 0) {
        int acc = 0;
        for (int i = 0; i < 256; i++) { int v = part[i]; part[i] = acc; acc += v; }
    }
    __syncthreads();
    int acc = part[t];
    for (int i = start; i < end; i++) { offsets[i] = acc; acc += counts[i]; }
    if (end == N_NODES && start < N_NODES) offsets[N_NODES] = acc;
}

__global__ void fill_kernel(const int* __restrict__ recv, const int* __restrict__ send,
                            const int* __restrict__ offsets,
                            int* __restrict__ cursor, int* __restrict__ ssorted,
                            int* __restrict__ rsorted) {
    int t = blockIdx.x * 256 + threadIdx.x;
    if (t < M_EDGES) {
        int r = recv[t];
        int pos = offsets[r] + atomicAdd(&cursor[r], 1);
        ssorted[pos] = send[t];
        rsorted[pos] = r;
    }
}

// ---- edge logits, fully edge-parallel grid-stride (persistent waves).
// Wave-iter processes 2 edges (32 lanes x 16B per K row); 2-slot manual unroll.
__global__ __launch_bounds__(256) void qk_csr_kernel(
    const int* __restrict__ ssorted, const int* __restrict__ rsorted,
    const float* __restrict__ Q, const unsigned short* __restrict__ Kb,
    float* __restrict__ qks, unsigned* __restrict__ gmax) {
    int wave_id = (blockIdx.x * 256 + threadIdx.x) >> 6;
    int lane = threadIdx.x & 63;
    int e_slot = lane >> 5;        // which edge of the pair
    int sl = lane & 31;            // 16B chunk within row
    const int nwaves = (gridDim.x * 256) >> 6;
    const int npairs = M_EDGES / 2;
    float wmax = -INFINITY;
    for (int pp = wave_id; pp < npairs; pp += 2 * nwaves) {
        int ppB = pp + nwaves;
        bool hasB = ppB < npairs;
        int pA = pp * 2 + e_slot;
        int pB = (hasB ? ppB * 2 : pp * 2) + e_slot;
        // independent slot loads — index/receiver (broadcast within half-wave)
        int sA = ssorted[pA], rA = rsorted[pA];
        int sB = ssorted[pB], rB = rsorted[pB];
        uint4 kA = *(const uint4*)(Kb + (size_t)sA * 256 + sl * 8);
        uint4 kB = *(const uint4*)(Kb + (size_t)sB * 256 + sl * 8);
        float4 qaA = *(const float4*)(Q + (size_t)rA * 256 + sl * 8);
        float4 qbA = *(const float4*)(Q + (size_t)rA * 256 + sl * 8 + 4);
        float4 qaB = *(const float4*)(Q + (size_t)rB * 256 + sl * 8);
        float4 qbB = *(const float4*)(Q + (size_t)rB * 256 + sl * 8 + 4);
        float dA = qaA.x * bflo(kA.x) + qaA.y * bfhi(kA.x)
                 + qaA.z * bflo(kA.y) + qaA.w * bfhi(kA.y)
                 + qbA.x * bflo(kA.z) + qbA.y * bfhi(kA.z)
                 + qbA.z * bflo(kA.w) + qbA.w * bfhi(kA.w);
        float dB = qaB.x * bflo(kB.x) + qaB.y * bfhi(kB.x)
                 + qaB.z * bflo(kB.y) + qaB.w * bfhi(kB.y)
                 + qbB.x * bflo(kB.z) + qbB.y * bfhi(kB.z)
                 + qbB.z * bflo(kB.w) + qbB.w * bfhi(kB.w);
        dA += __shfl_xor(dA, 1); dA += __shfl_xor(dA, 2);
        dB += __shfl_xor(dB, 1); dB += __shfl_xor(dB, 2);
        wmax = fmaxf(wmax, fmaxf(dA, dB));
        if ((sl & 3) == 0) {
            qks[(size_t)pA * 8 + (sl >> 2)] = dA;
            if (hasB) qks[(size_t)pB * 8 + (sl >> 2)] = dB;
        }
    }
    // wave max reduce + one atomic per wave
    wmax = fmaxf(wmax, __shfl_xor(wmax, 1));
    wmax = fmaxf(wmax, __shfl_xor(wmax, 2));
    wmax = fmaxf(wmax, __shfl_xor(wmax, 4));
    wmax = fmaxf(wmax, __shfl_xor(wmax, 8));
    wmax = fmaxf(wmax, __shfl_xor(wmax, 16));
    wmax = fmaxf(wmax, __shfl_xor(wmax, 32));
    if (lane == 0 && wmax > -INFINITY) atomicMax(gmax, enc_ord(wmax));
}

// ---- node aggregation: one wave per node (64 lanes x 4 cols = 256), grid-stride.
// Every lane sees every edge -> per-head softmax sum needs NO reduction; no LDS/sync.
__global__ __launch_bounds__(256) void node_agg_kernel(
    const int* __restrict__ offsets, const int* __restrict__ ssorted,
    const float* __restrict__ qks, const unsigned short* __restrict__ Vb,
    const unsigned* __restrict__ gmax, float* __restrict__ msg) {
    int wave_id = (blockIdx.x * 256 + threadIdx.x) >> 6;
    int lane = threadIdx.x & 63;   // columns lane*4 .. lane*4+3
    int h = lane >> 3;             // head of these columns
    const int nwaves = (gridDim.x * 256) >> 6;
    float scale = 3.0f / dec_ord(*gmax);
    for (int n = wave_id; n < N_NODES; n += nwaves) {
        int off = offsets[n];
        int deg = offsets[n + 1] - off;
        float sum = 0.f, a0 = 0.f, a1 = 0.f, a2 = 0.f, a3 = 0.f;
        for (int b = 0; b < deg; b += 64) {
            int bn = min(64, deg - b);
            int idxb = ssorted[off + b + min(lane, bn - 1)];  // coalesced index batch
            #define VROW(i) (*(const uint2*)(Vb + \
                (size_t)__shfl(idxb, min((i), bn - 1)) * 256 + lane * 4))
            #define QKL(i) qks[(size_t)(off + b + min((i), bn - 1)) * 8 + h]
            uint2 v0 = VROW(0);
            uint2 v1 = VROW(1);
            float q0 = QKL(0);
            float q1 = QKL(1);
            for (int i = 0; i < bn; i++) {
                uint2 vc = v0; v0 = v1; v1 = VROW(i + 2);
                float qc = q0; q0 = q1; q1 = QKL(i + 2);
                float a = __expf(qc * scale);
                sum += a;
                a0 += a * bflo(vc.x); a1 += a * bfhi(vc.x);
                a2 += a * bflo(vc.y); a3 += a * bfhi(vc.y);
            }
            #undef VROW
            #undef QKL
        }
        float inv = (deg > 0) ? 1.0f / (sum * 5.65685424949238f) : 0.f;  // sqrt(32)
        *(float4*)(msg + (size_t)n * 256 + lane * 4) =
            make_float4(fmaxf(a0 * inv, 0.f), fmaxf(a1 * inv, 0.f),
                        fmaxf(a2 * inv, 0.f), fmaxf(a3 * inv, 0.f));
    }
}

extern "C" void kernel_launch(void* const* d_in, const int* in_sizes, int n_in,
                              void* d_out, int out_size, void* d_ws, size_t ws_size,
                              hipStream_t stream) {
    const float* x    = (const float*)d_in[0];
    const int*   edge = (const int*)d_in[1];
    const int*   recv = edge;
    const int*   send = edge + M_EDGES;
    const float* Wk   = (const float*)d_in[2];
    const float* bk   = (const float*)d_in[3];
    const float* Wq   = (const float*)d_in[4];
    const float* bq   = (const float*)d_in[5];
    const float* Wv   = (const float*)d_in[6];
    const float* bv   = (const float*)d_in[7];
    const float* Wagg = (const float*)d_in[8];
    const float* bagg = (const float*)d_in[9];
    const float* Wff  = (const float*)d_in[10];
    const float* bff  = (const float*)d_in[11];
    float* out = (float*)d_out;

    float*  Qbuf  = (float*)d_ws;
    float*  msg   = Qbuf + (size_t)N_NODES * 256;
    float*  qks   = msg + (size_t)N_NODES * 256;
    __bf16* Kbf   = (__bf16*)(qks + (size_t)M_EDGES * 8);
    __bf16* Vbf   = Kbf + (size_t)N_NODES * 256;
    int* counts   = (int*)(Vbf + (size_t)N_NODES * 256);
    int* cursor   = counts + N_NODES;
    int* offsets  = cursor + N_NODES;
    int* ssorted  = offsets + N_NODES + 1;
    unsigned* gmax = (unsigned*)(ssorted + M_EDGES);
    __bf16* wt    = (__bf16*)(gmax + 1);
    __bf16* WkH = wt;              __bf16* WkL = wt + 65536;
    __bf16* WqH = wt + 2 * 65536;  __bf16* WqL = wt + 3 * 65536;
    __bf16* WvH = wt + 4 * 65536;  __bf16* WvL = wt + 5 * 65536;
    __bf16* WaH = wt + 6 * 65536;  __bf16* WaL = wt + 7 * 65536;
    __bf16* WfH = wt + 8 * 65536;  __bf16* WfL = wt + 9 * 65536;
    // rsorted overlays msg: live only during fill->qk, before node_agg writes msg
    int* rsorted  = (int*)msg;
    float* hidden = Qbuf;  // reuse: Q dead after qk_csr_kernel

    dim3 blk(256);
    dim3 gemm_grid((N_NODES + 127) / 128, 2);
    dim3 edge_grid((M_EDGES + 255) / 256);

    hipLaunchKernelGGL(init_kernel, dim3((N_NODES + 255) / 256), blk, 0, stream,
                       counts, cursor, gmax);
    hipLaunchKernelGGL(wsplit_kernel, dim3(256), blk, 0, stream, Wk,   WkH, WkL);
    hipLaunchKernelGGL(wsplit_kernel, dim3(256), blk, 0, stream, Wq,   WqH, WqL);
    hipLaunchKernelGGL(wsplit_kernel, dim3(256), blk, 0, stream, Wv,   WvH, WvL);
    hipLaunchKernelGGL(wsplit_kernel, dim3(256), blk, 0, stream, Wagg, WaH, WaL);
    hipLaunchKernelGGL(wsplit_kernel, dim3(256), blk, 0, stream, Wff,  WfH, WfL);
    // projections (MFMA); K,V emitted as bf16, Q fp32
    hipLaunchKernelGGL(gemm_mfma, gemm_grid, blk, 0, stream, x, WkH, WkL, bk, nullptr,
                       (float*)nullptr, Kbf, N_NODES, 0);
    hipLaunchKernelGGL(gemm_mfma, gemm_grid, blk, 0, stream, x, WqH, WqL, bq, nullptr,
                       Qbuf, (__bf16*)nullptr, N_NODES, 0);
    hipLaunchKernelGGL(gemm_mfma, gemm_grid, blk, 0, stream, x, WvH, WvL, bv, nullptr,
                       (float*)nullptr, Vbf, N_NODES, 0);
    // CSR build
    hipLaunchKernelGGL(hist_kernel, edge_grid, blk, 0, stream, recv, counts);
    hipLaunchKernelGGL(scan_kernel, dim3(1), blk, 0, stream, counts, offsets);
    hipLaunchKernelGGL(fill_kernel, edge_grid, blk, 0, stream, recv, send, offsets,
                       cursor, ssorted, rsorted);
    // edge logits + global max (persistent, edge-parallel)
    hipLaunchKernelGGL(qk_csr_kernel, dim3(1024), blk, 0, stream,
                       ssorted, rsorted, Qbuf, (const unsigned short*)Kbf, qks, gmax);
    // segment softmax + aggregate (persistent, wave-per-node)
    hipLaunchKernelGGL(node_agg_kernel, dim3(1024), blk, 0, stream,
                       offsets, ssorted, qks, (const unsigned short*)Vbf, gmax, msg);
    // output MLP (MFMA)
    hipLaunchKernelGGL(gemm_mfma, gemm_grid, blk, 0, stream, msg, WaH, WaL, bagg, nullptr,
                       hidden, (__bf16*)nullptr, N_NODES, 1);
    hipLaunchKernelGGL(gemm_mfma, gemm_grid, blk, 0, stream, hidden, WfH, WfL, bff, x,
                       out, (__bf16*)nullptr, N_NODES, 1);
}